// Round 7
// baseline (7993.352 us; speedup 1.0000x reference)
//
#include <hip/hip_runtime.h>
#include <hip/hip_fp16.h>
#include <math.h>

#define BB 8
#define SMEMN 128
#define DD 512
#define HDIM 64
#define DFFN 2048
#define NLAYER 3
#define VV 128
#define LLEN 32
#define SOS_T 1
#define EOS_T 2
#define PAD_T 0
#define NB 256
#define XP 1040          // xs row pitch (floats)
#define RP 520           // rs row pitch (floats)
#define WLD 520          // weight col pitch (halfs), K=512 mats
#define WLD2 2056        // ffn2 col pitch (halfs), K=2048
#define EMB_SCALE 22.62741699796952f

// LDS weight offsets (halfs)
#define OFF_QKV   0       // 2 layers x 8 cols x 520
#define OFF_SAOUT 8320    // 3 x 2 x 520
#define OFF_CAQ   11440
#define OFF_CAOUT 14560
#define OFF_FFN1  17680   // 3 x 8 x 520
#define OFF_FFN2  30160   // 3 x 2 x 2056
#define WTOT      42496

// ---- agent-scope (sc1) accessors: coherence-point access, no cache inv needed
__device__ __forceinline__ float cload(const float* p) {
    return __hip_atomic_load(p, __ATOMIC_RELAXED, __HIP_MEMORY_SCOPE_AGENT);
}
__device__ __forceinline__ float2 cload2(const float* p) {
    unsigned long long u = __hip_atomic_load((const unsigned long long*)p,
                                             __ATOMIC_RELAXED, __HIP_MEMORY_SCOPE_AGENT);
    union { unsigned long long u; float2 f; } c; c.u = u; return c.f;
}
__device__ __forceinline__ void cstore(float* p, float v) {
    __hip_atomic_store(p, v, __ATOMIC_RELAXED, __HIP_MEMORY_SCOPE_AGENT);
}
__device__ __forceinline__ int icload(const int* p) {
    return __hip_atomic_load(p, __ATOMIC_RELAXED, __HIP_MEMORY_SCOPE_AGENT);
}
__device__ __forceinline__ void icstore(int* p, int v) {
    __hip_atomic_store(p, v, __ATOMIC_RELAXED, __HIP_MEMORY_SCOPE_AGENT);
}

// ---------------------------------------------------------------- prologue
__global__ __launch_bounds__(512) void k_init(int* __restrict__ tokens, float* __restrict__ peR) {
    int i = threadIdx.x;
    if (i < BB * (LLEN + 1)) tokens[i] = (i % (LLEN + 1) == 0) ? SOS_T : PAD_T;
    for (int idx = i; idx < LLEN * DD; idx += 512) {
        int t = idx >> 9, d = idx & 511;
        int pos = (t == 0) ? 0 : (t + 1);
        float freq = expf((float)(d & ~1) * (-9.210340371976184f / 512.f));
        float ang = (float)pos * freq;
        peR[idx] = (d & 1) ? cosf(ang) : sinf(ang);
    }
}

// fp32 [L][K][N] (optionally row-scaled by g[L][K]) -> fp16 [L][N][KPAD]
__global__ __launch_bounds__(256) void t16pad(
    const float* __restrict__ src, const float* __restrict__ g,
    __half* __restrict__ dst, int K, int N, int KPAD)
{
    __shared__ float tile[32][33];
    int z = blockIdx.z;
    int k0 = blockIdx.x * 32, n0 = blockIdx.y * 32;
    const float* s = src + (size_t)z * K * N;
    __half* d = dst + (size_t)z * N * KPAD;
    int r = threadIdx.x >> 5, c = threadIdx.x & 31;
    #pragma unroll
    for (int i = 0; i < 4; i++) {
        int kk = k0 + r + i * 8;
        float gv = g ? g[(size_t)z * K + kk] : 1.f;
        tile[r + i * 8][c] = s[(size_t)kk * N + n0 + c] * gv;
    }
    __syncthreads();
    #pragma unroll
    for (int i = 0; i < 4; i++)
        d[(size_t)(n0 + r + i * 8) * KPAD + k0 + c] = (__half)tile[c][r + i * 8];
}

// SGW[c] = sum_k g[k] W[k][c]; BW[c] = sum_k b[k] W[k][c] + bias[c]  (fp32 exact)
__global__ __launch_bounds__(256) void k_colvec(
    const float* __restrict__ W, const float* __restrict__ g, const float* __restrict__ b,
    const float* __restrict__ bias, float* __restrict__ SGW, float* __restrict__ BW,
    int K, int N)
{
    int z = blockIdx.y;
    int c = blockIdx.x * 256 + threadIdx.x;
    if (c >= N) return;
    const float* Wz = W + (size_t)z * K * N;
    float sg = 0.f, bw = 0.f;
    for (int k = 0; k < K; ++k) {
        float w = Wz[(size_t)k * N + c];
        sg += g[(size_t)z * K + k] * w;
        bw += b[(size_t)z * K + k] * w;
    }
    SGW[(size_t)z * N + c] = sg;
    BW[(size_t)z * N + c] = bw + bias[(size_t)z * N + c];
}

// EQ[v] = (emb[v]*scale) @ Wqkv0 + bqkv0 ; PEQ[t] = peR[t] @ Wqkv0
__global__ __launch_bounds__(256) void k_eqpeq(
    const float* __restrict__ emb, const float* __restrict__ peR,
    const float* __restrict__ W0, const float* __restrict__ b0,
    float* __restrict__ EQ, float* __restrict__ PEQ)
{
    __shared__ float x[DD];
    int row = blockIdx.x, tid = threadIdx.x;
    bool isE = row < VV;
    for (int k = tid; k < DD; k += 256)
        x[k] = isE ? emb[(size_t)row * DD + k] * EMB_SCALE : peR[(row - VV) * DD + k];
    __syncthreads();
    for (int c = tid; c < 3 * DD; c += 256) {
        float a = isE ? b0[c] : 0.f;
        for (int k = 0; k < DD; ++k) a += x[k] * W0[(size_t)k * (3 * DD) + c];
        if (isE) EQ[(size_t)row * (3 * DD) + c] = a;
        else     PEQ[(size_t)(row - VV) * (3 * DD) + c] = a;
    }
}

// qkv0 / x0 for t=0 (token = SOS)
__global__ __launch_bounds__(256) void k_seed(
    const float* __restrict__ EQ, const float* __restrict__ PEQ,
    const float* __restrict__ emb, const float* __restrict__ peR,
    float* __restrict__ qbuf, float* __restrict__ Ksa, float* __restrict__ Vsa,
    float* __restrict__ x0buf)
{
    int b = blockIdx.x, tid = threadIdx.x;
    for (int c = tid; c < 3 * DD; c += 256) {
        float v = EQ[(size_t)SOS_T * (3 * DD) + c] + PEQ[c];
        if (c < DD)            qbuf[b * DD + c] = v;
        else if (c < 2 * DD)   Ksa[((size_t)b * LLEN) * DD + (c - DD)] = v;
        else                   Vsa[((size_t)b * LLEN) * DD + (c - 2 * DD)] = v;
    }
    for (int c = tid; c < DD; c += 256)
        x0buf[b * DD + c] = emb[(size_t)SOS_T * DD + c] * EMB_SCALE + peR[c];
}

// memory @ ca_kv_w (hoisted, fp32)
__global__ __launch_bounds__(256) void memkv_kernel(
    const float* __restrict__ mem, const float* __restrict__ Wkv, const float* __restrict__ bkv,
    float* __restrict__ Kmem, float* __restrict__ Vmem)
{
    int l = blockIdx.z;
    const float* Wl = Wkv + (size_t)l * DD * (2 * DD);
    const float* bl = bkv + l * (2 * DD);
    int brow = blockIdx.y * 64, bcol = blockIdx.x * 64;
    __shared__ float As[64][20];
    __shared__ float Bs[16][68];
    int tid = threadIdx.x;
    int ty = tid / 16, tx = tid % 16;
    float acc[4][4] = {};
    for (int k0 = 0; k0 < DD; k0 += 16) {
        {
            int r = tid >> 2, kk = (tid & 3) * 4;
            const float4 av = *(const float4*)(mem + (size_t)(brow + r) * DD + k0 + kk);
            As[r][kk] = av.x; As[r][kk + 1] = av.y; As[r][kk + 2] = av.z; As[r][kk + 3] = av.w;
        }
        {
            int kb = tid >> 4, j = (tid & 15) * 4;
            const float4 bv = *(const float4*)(Wl + (size_t)(k0 + kb) * (2 * DD) + bcol + j);
            Bs[kb][j] = bv.x; Bs[kb][j + 1] = bv.y; Bs[kb][j + 2] = bv.z; Bs[kb][j + 3] = bv.w;
        }
        __syncthreads();
        #pragma unroll
        for (int kk2 = 0; kk2 < 16; kk2++) {
            float a0 = As[ty * 4 + 0][kk2], a1 = As[ty * 4 + 1][kk2];
            float a2 = As[ty * 4 + 2][kk2], a3 = As[ty * 4 + 3][kk2];
            float b0 = Bs[kk2][tx * 4 + 0], b1 = Bs[kk2][tx * 4 + 1];
            float b2 = Bs[kk2][tx * 4 + 2], b3 = Bs[kk2][tx * 4 + 3];
            acc[0][0] += a0 * b0; acc[0][1] += a0 * b1; acc[0][2] += a0 * b2; acc[0][3] += a0 * b3;
            acc[1][0] += a1 * b0; acc[1][1] += a1 * b1; acc[1][2] += a1 * b2; acc[1][3] += a1 * b3;
            acc[2][0] += a2 * b0; acc[2][1] += a2 * b1; acc[2][2] += a2 * b2; acc[2][3] += a2 * b3;
            acc[3][0] += a3 * b0; acc[3][1] += a3 * b1; acc[3][2] += a3 * b2; acc[3][3] += a3 * b3;
        }
        __syncthreads();
    }
    for (int i = 0; i < 4; i++)
        for (int j = 0; j < 4; j++) {
            int row = brow + ty * 4 + i, colg = bcol + tx * 4 + j;
            float v = acc[i][j] + bl[colg];
            if (colg < DD) Kmem[((size_t)l * (BB * SMEMN) + row) * DD + colg] = v;
            else           Vmem[((size_t)l * (BB * SMEMN) + row) * DD + (colg - DD)] = v;
        }
}

// ----------------------------- dependency sync: arrive + prefix wait
__device__ __forceinline__ void garrive(int* flags, int gen, int bid, int tid) {
    asm volatile("s_waitcnt vmcnt(0)" ::: "memory");
    __syncthreads();                       // all waves drained
    if (tid == 0) icstore(flags + bid, gen);
}
// wait until flags[0..nf) >= gen  (nf even; 128 pollers x u64 pairs)
__device__ __forceinline__ void gwait(const int* flags, int gen, int tid, int nf) {
    const int np = nf >> 1;
    if (tid < np) {
        const unsigned long long* f2 = (const unsigned long long*)flags;
        int spins = 0;
        for (;;) {
            unsigned long long v = __hip_atomic_load(f2 + tid, __ATOMIC_RELAXED,
                                                     __HIP_MEMORY_SCOPE_AGENT);
            int lo = (int)(v & 0xffffffffu), hi = (int)(v >> 32);
            if (lo >= gen && hi >= gen) break;
            if (spins > 32) __builtin_amdgcn_s_sleep(2);   // tight-spin first
            if (++spins > (1 << 17)) break;                // escape hatch
        }
    }
    __syncthreads();
}

// -------------- stage 8x512 contiguously (+ stats via shfl butterfly)
// thread tid, chunk u -> row u, cols [2*tid, 2*tid+1]  (2-way bank alias = free)
__device__ __forceinline__ void stage_cs(
    float* dst, int pitch, const float* src, float* mO, float* rO,
    float* scr, int tid, int dostats)
{
    const int wv = tid >> 6, ln = tid & 63;
    float sum[8], sq[8];
    #pragma unroll
    for (int u = 0; u < 8; ++u) {
        float2 v = cload2(src + u * 512 + tid * 2);
        *(float2*)(dst + u * pitch + tid * 2) = v;
        sum[u] = v.x + v.y; sq[u] = v.x * v.x + v.y * v.y;
    }
    if (dostats) {
        #pragma unroll
        for (int u = 0; u < 8; ++u) {
            #pragma unroll
            for (int off = 32; off; off >>= 1) {
                sum[u] += __shfl_xor(sum[u], off);
                sq[u]  += __shfl_xor(sq[u], off);
            }
        }
        if (ln == 0) {
            #pragma unroll
            for (int u = 0; u < 8; ++u) {
                scr[u * 4 + wv] = sum[u]; scr[32 + u * 4 + wv] = sq[u];
            }
        }
        __syncthreads();
        if (tid < 8) {
            float s = scr[tid*4] + scr[tid*4+1] + scr[tid*4+2] + scr[tid*4+3];
            float q = scr[32+tid*4] + scr[32+tid*4+1] + scr[32+tid*4+2] + scr[32+tid*4+3];
            float m = s * (1.f / 512.f);
            mO[tid] = m; rO[tid] = rsqrtf(q * (1.f / 512.f) - m * m + 1e-5f);
        }
    }
    __syncthreads();
}

// stage one 8x1024 chunk of hb contiguously into xs
__device__ __forceinline__ void stage_hb(float* xs_, const float* hb, int ch, int tid) {
    #pragma unroll
    for (int u = 0; u < 16; ++u) {
        int i = u * 256 + tid;
        int r = i >> 9, c2 = i & 511;
        float2 v = cload2(hb + r * DFFN + ch * 1024 + c2 * 2);
        *(float2*)(xs_ + r * XP + c2 * 2) = v;
    }
}

// ------------------------------------------------------------ GEMV pieces
template <int NCOL, int KTOT, int PITCH>
__device__ __forceinline__ void gemv_accum(
    const __half* wcol0, int ldw, int wkoff, const float* xsL, float acc[8], int tid)
{
    constexpr int NKS = 256 / NCOL;
    const int c = tid / NKS, ks = tid % NKS;
    const __half* w = wcol0 + (size_t)c * ldw + wkoff;
    #pragma unroll
    for (int j = 0; j < KTOT / (NKS * 4); ++j) {
        int k = j * (NKS * 4) + ks * 4;
        const __half2* w2 = (const __half2*)(w + k);
        float2 f0 = __half22float2(w2[0]);
        float2 f1 = __half22float2(w2[1]);
        #pragma unroll
        for (int r = 0; r < 8; ++r) {
            const float4 xv = *(const float4*)(xsL + r * PITCH + k);
            acc[r] += xv.x * f0.x + xv.y * f0.y + xv.z * f1.x + xv.w * f1.y;
        }
    }
}

template <int INLN, int RESMODE, int RELU, int ROUTE>
__device__ __forceinline__ void emit_one(
    int out_i, float v, int gcol0,
    const float* SGW, const float* BWp,
    const float* mS_, const float* rS_,
    const float* rsL, const float* rmS_, const float* rrS_,
    const float* resg, const float* resb,
    float* out, int outN, float* qb, float* ksa, float* vsa)
{
    int c2 = out_i >> 3, r = out_i & 7;
    int g = gcol0 + c2;
    if (INLN) v = rS_[r] * (v - mS_[r] * SGW[g]);
    v += BWp[g];
    if (RELU) v = fmaxf(v, 0.f);
    if (RESMODE == 1) v += rsL[r * RP + g];
    if (RESMODE == 2) {
        float rv = rsL[r * RP + g];
        v += (rv - rmS_[r]) * rrS_[r] * resg[g] + resb[g];
    }
    if (ROUTE) {
        if (g < DD)            cstore(qb + r * DD + g, v);
        else if (g < 2 * DD)   cstore(ksa + (size_t)r * (LLEN * DD) + (g - DD), v);
        else                   cstore(vsa + (size_t)r * (LLEN * DD) + (g - 2 * DD), v);
    } else {
        cstore(out + (size_t)r * outN + g, v);
    }
}

template <int NCOL, int INLN, int RESMODE, int RELU, int ROUTE>
__device__ __forceinline__ void gemv_finish(
    float acc[8], float* part, int tid, int gcol0,
    const float* SGW, const float* BWp,
    const float* mS_, const float* rS_,
    const float* rsL, const float* rmS_, const float* rrS_,
    const float* resg, const float* resb,
    float* out, int outN, float* qb, float* ksa, float* vsa)
{
    constexpr int NKS = 256 / NCOL, PP = NKS + 1;
    const int c = tid / NKS, ks = tid % NKS;
    #pragma unroll
    for (int r = 0; r < 8; ++r) part[(c * 8 + r) * PP + ks] = acc[r];
    __syncthreads();
    if (NCOL == 2) {
        int out_i = tid >> 4, t16 = tid & 15;
        float v = 0.f;
        #pragma unroll
        for (int j = 0; j < 8; ++j) v += part[out_i * PP + t16 + 16 * j];
        for (int off = 8; off; off >>= 1) v += __shfl_down(v, off, 16);
        if (t16 == 0)
            emit_one<INLN, RESMODE, RELU, ROUTE>(out_i, v, gcol0, SGW, BWp, mS_, rS_,
                                                 rsL, rmS_, rrS_, resg, resb, out, outN, qb, ksa, vsa);
    } else {  // NCOL == 8, NKS = 32
        int out_i = tid >> 2, t4 = tid & 3;
        float v = 0.f;
        #pragma unroll
        for (int j = 0; j < 8; ++j) v += part[out_i * PP + t4 + 4 * j];
        v += __shfl_down(v, 2, 4); v += __shfl_down(v, 1, 4);
        if (t4 == 0)
            emit_one<INLN, RESMODE, RELU, ROUTE>(out_i, v, gcol0, SGW, BWp, mS_, rS_,
                                                 rsL, rmS_, rrS_, resg, resb, out, outN, qb, ksa, vsa);
    }
    __syncthreads();
}

// ---------------------------------------------------------------- megakernel
struct MegaParams {
    const float *emb;
    const float *sa_out_b, *ca_out_b, *ffn_b2;
    const float *ln1_g, *ln1_b, *ln2_g, *ln2_b, *ln3_g, *ln3_b;
    const __half *qkvGW16, *saout16, *caq16, *caout16, *ffn116, *ffn216, *clfGW16;
    const float *qkvSGW, *qkvBW, *caqSGW, *caqBW, *ffn1SGW, *ffn1BW, *clfSGW, *clfBW;
    const float *EQ, *PEQ, *peR;
    int *tokens, *flags;
    float *Kmem, *Vmem, *Ksa, *Vsa;
    float *qbuf, *attnb, *y1, *qca, *cat, *y2, *hb, *y3, *x0buf;
    float *out_logits, *out_sampled;
};

__device__ __forceinline__ void cp16(__half* dst, const __half* src, int halfs, int tid) {
    const int4* s = (const int4*)src;
    int4* d = (int4*)dst;
    int n = halfs >> 3;
    for (int i = tid; i < n; i += 256) d[i] = s[i];
}

__global__ __launch_bounds__(256, 1) void mega_kernel(MegaParams p) {
    __shared__ __align__(16) __half wlds[WTOT];   // 85.0 KB
    __shared__ float xs[BB * XP];                  // 33.3 KB
    __shared__ float rs[BB * RP];                  // 16.6 KB
    __shared__ float part[2112];                   // 8.4 KB
    __shared__ float scr[64];
    __shared__ float mS[8], rS[8], rmS[8], rrS[8], clfred[12];
    __shared__ int   tokLDS;
    __shared__ float argv[2];
    __shared__ int   argi[2];
    const int tid = threadIdx.x, bid = blockIdx.x;
    int g = 0, prevN = 256;

    // ---- one-time LDS weight fill ----
    if (bid < 192) {
        cp16(wlds + OFF_QKV,        p.qkvGW16 + ((size_t)0 * 1536 + bid * 8) * WLD, 8 * WLD, tid);
        cp16(wlds + OFF_QKV + 4160, p.qkvGW16 + ((size_t)1 * 1536 + bid * 8) * WLD, 8 * WLD, tid);
    }
    for (int l = 0; l < NLAYER; ++l) {
        cp16(wlds + OFF_SAOUT + l * 1040, p.saout16 + ((size_t)l * 512 + bid * 2) * WLD, 2 * WLD, tid);
        cp16(wlds + OFF_CAQ   + l * 1040, p.caq16   + ((size_t)l * 512 + bid * 2) * WLD, 2 * WLD, tid);
        cp16(wlds + OFF_CAOUT + l * 1040, p.caout16 + ((size_t)l * 512 + bid * 2) * WLD, 2 * WLD, tid);
        cp16(wlds + OFF_FFN1  + l * 4160, p.ffn116  + ((size_t)l * 2048 + bid * 8) * WLD, 8 * WLD, tid);
        cp16(wlds + OFF_FFN2  + l * 4112, p.ffn216  + ((size_t)l * 512 + bid * 2) * WLD2, 2 * WLD2, tid);
    }
    __syncthreads();

    for (int t = 0; t < LLEN; ++t) {
        for (int l = 0; l < NLAYER; ++l) {
            // ---- P1 qkv (l>=1): LN3-folded GEMV, 192 blocks x 8 cols ----
            if (l > 0) {
                gwait(p.flags, g, tid, prevN);
                if (bid < 192) {
                    stage_cs(xs, XP, p.y3, mS, rS, scr, tid, 1);
                    float acc[8] = {};
                    gemv_accum<8, 512, XP>(wlds + OFF_QKV + (l - 1) * 4160, WLD, 0, xs, acc, tid);
                    gemv_finish<8, 1, 0, 0, 1>(acc, part, tid, bid * 8,
                        p.qkvSGW + (l - 1) * 1536, p.qkvBW + (l - 1) * 1536, mS, rS,
                        nullptr, nullptr, nullptr, nullptr, nullptr,
                        nullptr, 0, p.qbuf,
                        p.Ksa + ((size_t)(l * 8) * LLEN + t) * DD,
                        p.Vsa + ((size_t)(l * 8) * LLEN + t) * DD);
                }
                ++g; garrive(p.flags, g, bid, tid); prevN = 192;
            }

            // ---- P2 self-attention (64 blocks) ----
            gwait(p.flags, g, tid, prevN);
            if (bid < 64) {
                const int b = bid >> 3, h = bid & 7;
                float* qsh = part;        // 64
                float* sc  = part + 64;   // 32
                float* po  = part + 128;  // 256
                if (tid < 64) qsh[tid] = cload(p.qbuf + b * DD + h * HDIM + tid);
                __syncthreads();
                const int w = tid >> 6, lane = tid & 63;
                const float* Kb = p.Ksa + ((size_t)(l * 8 + b)) * (LLEN * DD) + h * HDIM;
                for (int j = w; j <= t; j += 4) {
                    const float* kp = Kb + (size_t)j * DD + lane;
                    float kv = (j == t) ? cload(kp) : *kp;   // row t is fresh this step
                    float v = qsh[lane] * kv;
                    for (int off = 32; off; off >>= 1) v += __shfl_down(v, off);
                    if (lane == 0) sc[j] = v * 0.125f;
                }
                __syncthreads();
                if (tid < 64) {
                    float s = (tid <= t) ? sc[tid] : -1e30f;
                    float mx = s;
                    for (int off = 32; off; off >>= 1) mx = fmaxf(mx, __shfl_xor(mx, off));
                    float pe = (tid <= t) ? expf(s - mx) : 0.f;
                    float sum = pe;
                    for (int off = 32; off; off >>= 1) sum += __shfl_xor(sum, off);
                    if (tid <= t) sc[tid] = pe / sum;
                }
                __syncthreads();
                {
                    const float* Vb = p.Vsa + ((size_t)(l * 8 + b)) * (LLEN * DD) + h * HDIM;
                    float o = 0.f;
                    for (int j = w; j <= t; j += 4) {
                        const float* vp = Vb + (size_t)j * DD + lane;
                        float vv = (j == t) ? cload(vp) : *vp;
                        o += sc[j] * vv;
                    }
                    po[w * 64 + lane] = o;
                }
                __syncthreads();
                if (tid < 64)
                    cstore(p.attnb + b * DD + h * HDIM + tid,
                           po[tid] + po[64 + tid] + po[128 + tid] + po[192 + tid]);
            }
            ++g; garrive(p.flags, g, bid, tid); prevN = 64;

            // ---- P3 saout + residual (raw embed l=0 | LN3-fold l>=1) ----
            gwait(p.flags, g, tid, prevN);
            {
                stage_cs(xs, XP, p.attnb, mS, rS, scr, tid, 0);
                if (l == 0) stage_cs(rs, RP, p.x0buf, rmS, rrS, scr, tid, 0);
                else        stage_cs(rs, RP, p.y3,    rmS, rrS, scr, tid, 1);
                float acc[8] = {};
                gemv_accum<2, 512, XP>(wlds + OFF_SAOUT + l * 1040, WLD, 0, xs, acc, tid);
                if (l == 0)
                    gemv_finish<2, 0, 1, 0, 0>(acc, part, tid, bid * 2,
                        nullptr, p.sa_out_b + l * DD, nullptr, nullptr,
                        rs, nullptr, nullptr, nullptr, nullptr,
                        p.y1, DD, nullptr, nullptr, nullptr);
                else
                    gemv_finish<2, 0, 2, 0, 0>(acc, part, tid, bid * 2,
                        nullptr, p.sa_out_b + l * DD, nullptr, nullptr,
                        rs, rmS, rrS, p.ln3_g + (l - 1) * DD, p.ln3_b + (l - 1) * DD,
                        p.y1, DD, nullptr, nullptr, nullptr);
            }
            ++g; garrive(p.flags, g, bid, tid); prevN = 256;

            // ---- P4 ca_q: stage y1->rs (stats kept for P6), LN1-folded GEMV ----
            gwait(p.flags, g, tid, prevN);
            {
                stage_cs(rs, RP, p.y1, rmS, rrS, scr, tid, 1);
                float acc[8] = {};
                gemv_accum<2, 512, RP>(wlds + OFF_CAQ + l * 1040, WLD, 0, rs, acc, tid);
                gemv_finish<2, 1, 0, 0, 0>(acc, part, tid, bid * 2,
                    p.caqSGW + l * DD, p.caqBW + l * DD, rmS, rrS,
                    nullptr, nullptr, nullptr, nullptr, nullptr,
                    p.qca, DD, nullptr, nullptr, nullptr);
            }
            ++g; garrive(p.flags, g, bid, tid); prevN = 256;

            // ---- P5 cross-attention (64 blocks; rs/rmS/rrS preserved) ----
            gwait(p.flags, g, tid, prevN);
            if (bid < 64) {
                const int b = bid >> 3, h = bid & 7;
                float* qsh = part;         // 64
                float* sc  = part + 64;    // 128
                float* po  = part + 192;   // 128
                if (tid < 64) qsh[tid] = cload(p.qca + b * DD + h * HDIM + tid);
                __syncthreads();
                if (tid < 128) {
                    const float* kp = p.Kmem + (((size_t)(l * 8 + b)) * SMEMN + tid) * DD + h * HDIM;
                    float s = 0.f;
                    #pragma unroll 8
                    for (int d = 0; d < HDIM; ++d) s += qsh[d] * kp[d];
                    sc[tid] = s * 0.125f;
                }
                __syncthreads();
                if (tid < 64) {
                    float s0 = sc[tid], s1 = sc[tid + 64];
                    float mx = fmaxf(s0, s1);
                    for (int off = 32; off; off >>= 1) mx = fmaxf(mx, __shfl_xor(mx, off));
                    float e0 = expf(s0 - mx), e1 = expf(s1 - mx);
                    float sum = e0 + e1;
                    for (int off = 32; off; off >>= 1) sum += __shfl_xor(sum, off);
                    sc[tid] = e0 / sum; sc[tid + 64] = e1 / sum;
                }
                __syncthreads();
                if (tid < 128) {
                    int d = tid & 63, half = tid >> 6;
                    const float* Vb = p.Vmem + (((size_t)(l * 8 + b)) * SMEMN + half * 64) * DD + h * HDIM + d;
                    float o = 0.f;
                    for (int j = 0; j < 64; ++j) o += sc[half * 64 + j] * Vb[(size_t)j * DD];
                    po[half * 64 + d] = o;
                }
                __syncthreads();
                if (tid < 64)
                    cstore(p.cat + b * DD + h * HDIM + tid, po[tid] + po[64 + tid]);
            }
            ++g; garrive(p.flags, g, bid, tid); prevN = 64;

            // ---- P6 caout + residual LN1(y1)-fold (reuse rs from P4) ----
            gwait(p.flags, g, tid, prevN);
            {
                stage_cs(xs, XP, p.cat, mS, rS, scr, tid, 0);
                float acc[8] = {};
                gemv_accum<2, 512, XP>(wlds + OFF_CAOUT + l * 1040, WLD, 0, xs, acc, tid);
                gemv_finish<2, 0, 2, 0, 0>(acc, part, tid, bid * 2,
                    nullptr, p.ca_out_b + l * DD, nullptr, nullptr,
                    rs, rmS, rrS, p.ln1_g + l * DD, p.ln1_b + l * DD,
                    p.y2, DD, nullptr, nullptr, nullptr);
            }
            ++g; garrive(p.flags, g, bid, tid); prevN = 256;

            // ---- P7 ffn1: stage y2->rs (stats kept for P8), LN2-folded + relu ----
            gwait(p.flags, g, tid, prevN);
            {
                stage_cs(rs, RP, p.y2, rmS, rrS, scr, tid, 1);
                float acc[8] = {};
                gemv_accum<8, 512, RP>(wlds + OFF_FFN1 + l * 4160, WLD, 0, rs, acc, tid);
                gemv_finish<8, 1, 0, 1, 0>(acc, part, tid, bid * 8,
                    p.ffn1SGW + l * DFFN, p.ffn1BW + l * DFFN, rmS, rrS,
                    nullptr, nullptr, nullptr, nullptr, nullptr,
                    p.hb, DFFN, nullptr, nullptr, nullptr);
            }
            ++g; garrive(p.flags, g, bid, tid); prevN = 256;

            // ---- P8 ffn2 (K=2048 in 2 chunks) + residual LN2(y2)-fold (rs reused) ----
            gwait(p.flags, g, tid, prevN);
            {
                float acc[8] = {};
                stage_hb(xs, p.hb, 0, tid);
                __syncthreads();
                gemv_accum<2, 1024, XP>(wlds + OFF_FFN2 + l * 4112, WLD2, 0, xs, acc, tid);
                __syncthreads();
                stage_hb(xs, p.hb, 1, tid);
                __syncthreads();
                gemv_accum<2, 1024, XP>(wlds + OFF_FFN2 + l * 4112, WLD2, 1024, xs, acc, tid);
                gemv_finish<2, 0, 2, 0, 0>(acc, part, tid, bid * 2,
                    nullptr, p.ffn_b2 + l * DD, nullptr, nullptr,
                    rs, rmS, rrS, p.ln2_g + l * DD, p.ln2_b + l * DD,
                    p.y3, DD, nullptr, nullptr, nullptr);
            }
            ++g; garrive(p.flags, g, bid, tid); prevN = 256;
        }

        // ---- CLF: LN3-folded logits + argmax + next-step qkv0/x0 lookup ----
        gwait(p.flags, g, tid, prevN);
        if (bid < 8) {
            const int b = bid;
            {
                float2 v = cload2(p.y3 + b * DD + tid * 2);
                rs[tid * 2] = v.x; rs[tid * 2 + 1] = v.y;
                float sum = v.x + v.y, sq = v.x * v.x + v.y * v.y;
                for (int off = 32; off; off >>= 1) {
                    sum += __shfl_down(sum, off); sq += __shfl_down(sq, off);
                }
                if ((tid & 63) == 0) { clfred[tid >> 6] = sum; clfred[4 + (tid >> 6)] = sq; }
                __syncthreads();
                if (tid == 0) {
                    float s = clfred[0] + clfred[1] + clfred[2] + clfred[3];
                    float q = clfred[4] + clfred[5] + clfred[6] + clfred[7];
                    float m = s * (1.f / 512.f);
                    clfred[8] = m; clfred[9] = rsqrtf(q * (1.f / 512.f) - m * m + 1e-5f);
                }
                __syncthreads();
            }
            {
                int cl = tid & 127, kh = tid >> 7;
                const __half2* w2 = (const __half2*)(p.clfGW16 + (size_t)cl * 512 + kh * 256);
                const float* xh = rs + kh * 256;
                float lg = 0.f;
                #pragma unroll 8
                for (int k2 = 0; k2 < 128; ++k2) {
                    float2 f = __half22float2(w2[k2]);
                    lg += xh[2 * k2] * f.x + xh[2 * k2 + 1] * f.y;
                }
                part[tid] = lg;
            }
            __syncthreads();
            if (tid < 128) {
                float m = clfred[8], ri = clfred[9];
                float lg = ri * ((part[tid] + part[128 + tid]) - m * p.clfSGW[tid]) + p.clfBW[tid];
                p.out_logits[((size_t)b * LLEN + t) * VV + tid] = lg;
                float bv = lg; int bi = tid;
                for (int off = 32; off; off >>= 1) {
                    float ov = __shfl_xor(bv, off); int oi = __shfl_xor(bi, off);
                    if (ov > bv || (ov == bv && oi < bi)) { bv = ov; bi = oi; }
                }
                if ((tid & 63) == 0) { argv[tid >> 6] = bv; argi[tid >> 6] = bi; }
            }
            __syncthreads();
            if (tid == 0) {
                int best = (argv[1] > argv[0] || (argv[1] == argv[0] && argi[1] < argi[0]))
                               ? argi[1] : argi[0];
                icstore(p.tokens + b * (LLEN + 1) + t + 1, best);
                tokLDS = best;
            }
            __syncthreads();
            if (t < LLEN - 1) {
                int tok = tokLDS, tn = t + 1;
                for (int c = tid; c < 3 * DD; c += 256) {
                    float v = p.EQ[(size_t)tok * (3 * DD) + c] + p.PEQ[(size_t)tn * (3 * DD) + c];
                    if (c < DD)          cstore(p.qbuf + b * DD + c, v);
                    else if (c < 2 * DD) cstore(p.Ksa + ((size_t)b * LLEN + tn) * DD + (c - DD), v);
                    else                 cstore(p.Vsa + ((size_t)b * LLEN + tn) * DD + (c - 2 * DD), v);
                }
                for (int c = tid; c < DD; c += 256)
                    cstore(p.x0buf + b * DD + c,
                           p.emb[(size_t)tok * DD + c] * EMB_SCALE + p.peR[(size_t)tn * DD + c]);
            }
        }
        ++g; garrive(p.flags, g, bid, tid); prevN = 8;
    }

    // ---- finalize sampled ----
    if (bid == 0) {
        gwait(p.flags, g, tid, 8);
        if (tid < BB) {
            int b = tid;
            int toks[LLEN + 1];
            for (int j = 0; j <= LLEN; j++) toks[j] = icload(p.tokens + b * (LLEN + 1) + j);
            int eos = 0;
            for (int j = 1; j <= LLEN; j++)
                if (toks[j] == EOS_T) { eos = j; break; }
            for (int j = 0; j <= LLEN; j++) {
                int v = toks[j];
                if (eos != 0 && j > eos + 1) v = PAD_T;
                p.out_sampled[b * (LLEN + 1) + j] = (float)v;
            }
        }
    }
}

// --------------------------------------------------------------------- host
extern "C" void kernel_launch(void* const* d_in, const int* in_sizes, int n_in,
                              void* d_out, int out_size, void* d_ws, size_t ws_size,
                              hipStream_t stream) {
    const float* memory   = (const float*)d_in[0];
    const float* emb      = (const float*)d_in[1];
    const float* sa_qkv_w = (const float*)d_in[2];
    const float* sa_qkv_b = (const float*)d_in[3];
    const float* sa_out_w = (const float*)d_in[4];
    const float* sa_out_b = (const float*)d_in[5];
    const float* ca_q_w   = (const float*)d_in[6];
    const float* ca_q_b   = (const float*)d_in[7];
    const float* ca_kv_w  = (const float*)d_in[8];
    const float* ca_kv_b  = (const float*)d_in[9];
    const float* ca_out_w = (const float*)d_in[10];
    const float* ca_out_b = (const float*)d_in[11];
    const float* ln1_g    = (const float*)d_in[12];
    const float* ln1_b    = (const float*)d_in[13];
    const float* ln2_g    = (const float*)d_in[14];
    const float* ln2_b    = (const float*)d_in[15];
    const float* ln3_g    = (const float*)d_in[16];
    const float* ln3_b    = (const float*)d_in[17];
    const float* ffn_w1   = (const float*)d_in[18];
    const float* ffn_b1   = (const float*)d_in[19];
    const float* ffn_w2   = (const float*)d_in[20];
    const float* ffn_b2   = (const float*)d_in[21];
    const float* clf_w    = (const float*)d_in[22];
    const float* clf_b    = (const float*)d_in[23];

    float* f   = (float*)d_ws;
    int*   wsI = (int*)d_ws;
    int* flags  = wsI;                 // 256 ints
    int* tokens = wsI + 256;           // 264 ints
    float* peR  = f + 1024;            // 32*512
    float* Kmem = peR + LLEN * DD;
    float* Vmem = Kmem + (size_t)NLAYER * BB * SMEMN * DD;
    float* Ksa  = Vmem + (size_t)NLAYER * BB * SMEMN * DD;
    float* Vsa  = Ksa  + (size_t)NLAYER * BB * LLEN * DD;
    float* qbuf = Vsa  + (size_t)NLAYER * BB * LLEN * DD;
    float* attnb= qbuf + BB * DD;
    float* y1   = attnb+ BB * DD;
    float* qca  = y1   + BB * DD;
    float* cat  = qca  + BB * DD;
    float* y2   = cat  + BB * DD;
    float* hb   = y2   + BB * DD;
    float* y3   = hb   + BB * DFFN;
    float* x0buf= y3   + BB * DD;
    float* EQ   = x0buf+ BB * DD;
    float* PEQ  = EQ   + (size_t)VV * 3 * DD;
    float* qkvSGW = PEQ + (size_t)LLEN * 3 * DD;
    float* qkvBW  = qkvSGW + 2 * 1536;
    float* caqSGW = qkvBW  + 2 * 1536;
    float* caqBW  = caqSGW + 3 * 512;
    float* ffn1SGW= caqBW  + 3 * 512;
    float* ffn1BW = ffn1SGW+ 3 * 2048;
    float* clfSGW = ffn1BW + 3 * 2048;
    float* clfBW  = clfSGW + 128;
    __half* qkvGW16 = (__half*)(clfBW + 128);
    __half* saout16 = qkvGW16 + (size_t)2 * 1536 * WLD;
    __half* caq16   = saout16 + (size_t)3 * 512 * WLD;
    __half* caout16 = caq16   + (size_t)3 * 512 * WLD;
    __half* ffn116  = caout16 + (size_t)3 * 512 * WLD;
    __half* ffn216  = ffn116  + (size_t)3 * 2048 * WLD;
    __half* clfGW16 = ffn216  + (size_t)3 * 512 * WLD2;

    float* out_logits  = (float*)d_out;
    float* out_sampled = out_logits + (size_t)BB * LLEN * VV;

    hipMemsetAsync(d_ws, 0, 4096, stream);   // flags + tokens region
    k_init<<<1, 512, 0, stream>>>(tokens, peR);

    t16pad<<<dim3(16, 48, 2), 256, 0, stream>>>(sa_qkv_w + (size_t)512 * 1536, ln3_g, qkvGW16, 512, 1536, WLD);
    t16pad<<<dim3(16, 16, 3), 256, 0, stream>>>(sa_out_w, nullptr, saout16, 512, 512, WLD);
    t16pad<<<dim3(16, 16, 3), 256, 0, stream>>>(ca_q_w,   ln1_g,   caq16,   512, 512, WLD);
    t16pad<<<dim3(16, 16, 3), 256, 0, stream>>>(ca_out_w, nullptr, caout16, 512, 512, WLD);
    t16pad<<<dim3(16, 64, 3), 256, 0, stream>>>(ffn_w1,   ln2_g,   ffn116,  512, 2048, WLD);
    t16pad<<<dim3(64, 16, 3), 256, 0, stream>>>(ffn_w2,   nullptr, ffn216,  2048, 512, WLD2);
    t16pad<<<dim3(16, 4, 1),  256, 0, stream>>>(clf_w,    ln3_g + 2 * 512, clfGW16, 512, 128, 512);

    k_colvec<<<dim3(6, 2), 256, 0, stream>>>(sa_qkv_w + (size_t)512 * 1536, ln3_g, ln3_b,
                                             sa_qkv_b + 1536, qkvSGW, qkvBW, 512, 1536);
    k_colvec<<<dim3(2, 3), 256, 0, stream>>>(ca_q_w, ln1_g, ln1_b, ca_q_b, caqSGW, caqBW, 512, 512);
    k_colvec<<<dim3(8, 3), 256, 0, stream>>>(ffn_w1, ln2_g, ln2_b, ffn_b1, ffn1SGW, ffn1BW, 512, 2048);
    k_colvec<<<dim3(1, 1), 256, 0, stream>>>(clf_w, ln3_g + 1024, ln3_b + 1024, clf_b,
                                             clfSGW, clfBW, 512, 128);

    k_eqpeq<<<VV + LLEN, 256, 0, stream>>>(emb, peR, sa_qkv_w, sa_qkv_b, EQ, PEQ);
    memkv_kernel<<<dim3(16, 16, 3), 256, 0, stream>>>(memory, ca_kv_w, ca_kv_b, Kmem, Vmem);
    k_seed<<<8, 256, 0, stream>>>(EQ, PEQ, emb, peR, qbuf, Ksa, Vsa, x0buf);

    MegaParams p;
    p.emb = emb;
    p.sa_out_b = sa_out_b; p.ca_out_b = ca_out_b; p.ffn_b2 = ffn_b2;
    p.ln1_g = ln1_g; p.ln1_b = ln1_b;
    p.ln2_g = ln2_g; p.ln2_b = ln2_b;
    p.ln3_g = ln3_g; p.ln3_b = ln3_b;
    p.qkvGW16 = qkvGW16; p.saout16 = saout16; p.caq16 = caq16; p.caout16 = caout16;
    p.ffn116 = ffn116; p.ffn216 = ffn216; p.clfGW16 = clfGW16;
    p.qkvSGW = qkvSGW; p.qkvBW = qkvBW; p.caqSGW = caqSGW; p.caqBW = caqBW;
    p.ffn1SGW = ffn1SGW; p.ffn1BW = ffn1BW; p.clfSGW = clfSGW; p.clfBW = clfBW;
    p.EQ = EQ; p.PEQ = PEQ; p.peR = peR;
    p.tokens = tokens; p.flags = flags;
    p.Kmem = Kmem; p.Vmem = Vmem; p.Ksa = Ksa; p.Vsa = Vsa;
    p.qbuf = qbuf; p.attnb = attnb; p.y1 = y1; p.qca = qca;
    p.cat = cat; p.y2 = y2; p.hb = hb; p.y3 = y3; p.x0buf = x0buf;
    p.out_logits = out_logits; p.out_sampled = out_sampled;

    mega_kernel<<<NB, 256, 0, stream>>>(p);
}

// Round 8
// 5986.367 us; speedup vs baseline: 1.3353x; 1.3353x over previous
//
#include <hip/hip_runtime.h>
#include <hip/hip_fp16.h>
#include <math.h>

#define BB 8
#define SMEMN 128
#define DD 512
#define HDIM 64
#define DFFN 2048
#define NLAYER 3
#define VV 128
#define LLEN 32
#define SOS_T 1
#define EOS_T 2
#define PAD_T 0
#define NB 256
#define RP 520           // activation row pitch (floats)
#define WLD 520          // weight col pitch (halfs), K=512 mats
#define WLD2 2056        // ffn2 col pitch (halfs), K=2048
#define KVP 66           // LDS KV row pitch (floats)
#define EMB_SCALE 22.62741699796952f

// LDS-resident weights: ffn1 + ffn2 only
#define OFF_FFN1  0          // 3 layers x 8 cols x 520
#define OFF_FFN2  12480      // 3 layers x 2 cols x 2056
#define WTOT      24816

// ---- agent-scope (sc1) accessors
__device__ __forceinline__ float cload(const float* p) {
    return __hip_atomic_load(p, __ATOMIC_RELAXED, __HIP_MEMORY_SCOPE_AGENT);
}
__device__ __forceinline__ float2 cload2(const float* p) {
    unsigned long long u = __hip_atomic_load((const unsigned long long*)p,
                                             __ATOMIC_RELAXED, __HIP_MEMORY_SCOPE_AGENT);
    union { unsigned long long u; float2 f; } c; c.u = u; return c.f;
}
__device__ __forceinline__ void cstore(float* p, float v) {
    __hip_atomic_store(p, v, __ATOMIC_RELAXED, __HIP_MEMORY_SCOPE_AGENT);
}
__device__ __forceinline__ int icload(const int* p) {
    return __hip_atomic_load(p, __ATOMIC_RELAXED, __HIP_MEMORY_SCOPE_AGENT);
}
__device__ __forceinline__ void icstore(int* p, int v) {
    __hip_atomic_store(p, v, __ATOMIC_RELAXED, __HIP_MEMORY_SCOPE_AGENT);
}

// ---------------------------------------------------------------- prologue
__global__ __launch_bounds__(512) void k_init(int* __restrict__ tokens, float* __restrict__ peR) {
    int i = threadIdx.x;
    if (i < BB * (LLEN + 1)) tokens[i] = (i % (LLEN + 1) == 0) ? SOS_T : PAD_T;
    for (int idx = i; idx < LLEN * DD; idx += 512) {
        int t = idx >> 9, d = idx & 511;
        int pos = (t == 0) ? 0 : (t + 1);
        float freq = expf((float)(d & ~1) * (-9.210340371976184f / 512.f));
        float ang = (float)pos * freq;
        peR[idx] = (d & 1) ? cosf(ang) : sinf(ang);
    }
}

// fp32 [Z][K][N] (optionally row-scaled by g[Z][K]) -> fp16 [Z][N][KPAD]
__global__ __launch_bounds__(256) void t16pad(
    const float* __restrict__ src, const float* __restrict__ g,
    __half* __restrict__ dst, int K, int N, int KPAD)
{
    __shared__ float tile[32][33];
    int z = blockIdx.z;
    int k0 = blockIdx.x * 32, n0 = blockIdx.y * 32;
    const float* s = src + (size_t)z * K * N;
    __half* d = dst + (size_t)z * N * KPAD;
    int r = threadIdx.x >> 5, c = threadIdx.x & 31;
    #pragma unroll
    for (int i = 0; i < 4; i++) {
        int kk = k0 + r + i * 8;
        float gv = g ? g[(size_t)z * K + kk] : 1.f;
        tile[r + i * 8][c] = s[(size_t)kk * N + n0 + c] * gv;
    }
    __syncthreads();
    #pragma unroll
    for (int i = 0; i < 4; i++)
        d[(size_t)(n0 + r + i * 8) * KPAD + k0 + c] = (__half)tile[c][r + i * 8];
}

// SGW[c] = sum_k g[k] W[k][c]; BW[c] = sum_k b[k] W[k][c] + bias[c]
__global__ __launch_bounds__(256) void k_colvec(
    const float* __restrict__ W, const float* __restrict__ g, const float* __restrict__ b,
    const float* __restrict__ bias, float* __restrict__ SGW, float* __restrict__ BW,
    int K, int N)
{
    int z = blockIdx.y;
    int c = blockIdx.x * 256 + threadIdx.x;
    if (c >= N) return;
    const float* Wz = W + (size_t)z * K * N;
    float sg = 0.f, bw = 0.f;
    for (int k = 0; k < K; ++k) {
        float w = Wz[(size_t)k * N + c];
        sg += g[(size_t)z * K + k] * w;
        bw += b[(size_t)z * K + k] * w;
    }
    SGW[(size_t)z * N + c] = sg;
    BW[(size_t)z * N + c] = bw + bias[(size_t)z * N + c];
}

// EQ[v] = (emb[v]*scale) @ Wqkv0 + bqkv0 ; PEQ[t] = peR[t] @ Wqkv0
__global__ __launch_bounds__(256) void k_eqpeq(
    const float* __restrict__ emb, const float* __restrict__ peR,
    const float* __restrict__ W0, const float* __restrict__ b0,
    float* __restrict__ EQ, float* __restrict__ PEQ)
{
    __shared__ float x[DD];
    int row = blockIdx.x, tid = threadIdx.x;
    bool isE = row < VV;
    for (int k = tid; k < DD; k += 256)
        x[k] = isE ? emb[(size_t)row * DD + k] * EMB_SCALE : peR[(row - VV) * DD + k];
    __syncthreads();
    for (int c = tid; c < 3 * DD; c += 256) {
        float a = isE ? b0[c] : 0.f;
        for (int k = 0; k < DD; ++k) a += x[k] * W0[(size_t)k * (3 * DD) + c];
        if (isE) EQ[(size_t)row * (3 * DD) + c] = a;
        else     PEQ[(size_t)(row - VV) * (3 * DD) + c] = a;
    }
}

// qkv0 / x0 for t=0 (token = SOS)
__global__ __launch_bounds__(256) void k_seed(
    const float* __restrict__ EQ, const float* __restrict__ PEQ,
    const float* __restrict__ emb, const float* __restrict__ peR,
    float* __restrict__ qbuf, float* __restrict__ Ksa, float* __restrict__ Vsa,
    float* __restrict__ x0buf)
{
    int b = blockIdx.x, tid = threadIdx.x;
    for (int c = tid; c < 3 * DD; c += 256) {
        float v = EQ[(size_t)SOS_T * (3 * DD) + c] + PEQ[c];
        if (c < DD)            qbuf[b * DD + c] = v;
        else if (c < 2 * DD)   Ksa[((size_t)b * LLEN) * DD + (c - DD)] = v;
        else                   Vsa[((size_t)b * LLEN) * DD + (c - 2 * DD)] = v;
    }
    for (int c = tid; c < DD; c += 256)
        x0buf[b * DD + c] = emb[(size_t)SOS_T * DD + c] * EMB_SCALE + peR[c];
}

// memory @ ca_kv_w (hoisted, fp32)
__global__ __launch_bounds__(256) void memkv_kernel(
    const float* __restrict__ mem, const float* __restrict__ Wkv, const float* __restrict__ bkv,
    float* __restrict__ Kmem, float* __restrict__ Vmem)
{
    int l = blockIdx.z;
    const float* Wl = Wkv + (size_t)l * DD * (2 * DD);
    const float* bl = bkv + l * (2 * DD);
    int brow = blockIdx.y * 64, bcol = blockIdx.x * 64;
    __shared__ float As[64][20];
    __shared__ float Bs[16][68];
    int tid = threadIdx.x;
    int ty = tid / 16, tx = tid % 16;
    float acc[4][4] = {};
    for (int k0 = 0; k0 < DD; k0 += 16) {
        {
            int r = tid >> 2, kk = (tid & 3) * 4;
            const float4 av = *(const float4*)(mem + (size_t)(brow + r) * DD + k0 + kk);
            As[r][kk] = av.x; As[r][kk + 1] = av.y; As[r][kk + 2] = av.z; As[r][kk + 3] = av.w;
        }
        {
            int kb = tid >> 4, j = (tid & 15) * 4;
            const float4 bv = *(const float4*)(Wl + (size_t)(k0 + kb) * (2 * DD) + bcol + j);
            Bs[kb][j] = bv.x; Bs[kb][j + 1] = bv.y; Bs[kb][j + 2] = bv.z; Bs[kb][j + 3] = bv.w;
        }
        __syncthreads();
        #pragma unroll
        for (int kk2 = 0; kk2 < 16; kk2++) {
            float a0 = As[ty * 4 + 0][kk2], a1 = As[ty * 4 + 1][kk2];
            float a2 = As[ty * 4 + 2][kk2], a3 = As[ty * 4 + 3][kk2];
            float b0 = Bs[kk2][tx * 4 + 0], b1 = Bs[kk2][tx * 4 + 1];
            float b2 = Bs[kk2][tx * 4 + 2], b3 = Bs[kk2][tx * 4 + 3];
            acc[0][0] += a0 * b0; acc[0][1] += a0 * b1; acc[0][2] += a0 * b2; acc[0][3] += a0 * b3;
            acc[1][0] += a1 * b0; acc[1][1] += a1 * b1; acc[1][2] += a1 * b2; acc[1][3] += a1 * b3;
            acc[2][0] += a2 * b0; acc[2][1] += a2 * b1; acc[2][2] += a2 * b2; acc[2][3] += a2 * b3;
            acc[3][0] += a3 * b0; acc[3][1] += a3 * b1; acc[3][2] += a3 * b2; acc[3][3] += a3 * b3;
        }
        __syncthreads();
    }
    for (int i = 0; i < 4; i++)
        for (int j = 0; j < 4; j++) {
            int row = brow + ty * 4 + i, colg = bcol + tx * 4 + j;
            float v = acc[i][j] + bl[colg];
            if (colg < DD) Kmem[((size_t)l * (BB * SMEMN) + row) * DD + colg] = v;
            else           Vmem[((size_t)l * (BB * SMEMN) + row) * DD + (colg - DD)] = v;
        }
}

// ----------------------------- relay grid barrier (r6 design — best measured)
__device__ __forceinline__ void gbar(int* flags, int* release, int gen, int bid, int tid) {
    asm volatile("s_waitcnt vmcnt(0)" ::: "memory");
    __syncthreads();
    if (bid == 0) {
        if (tid > 0) {
            int spins = 0;
            while (icload(flags + tid * 16) < gen) {
                __builtin_amdgcn_s_sleep(1);
                if (++spins > (1 << 16)) break;
            }
        }
        __syncthreads();
        if (tid < 8) icstore(release + tid * 16, gen);
    } else {
        if (tid == 0) {
            icstore(flags + bid * 16, gen);
            int spins = 0;
            while (icload(release + (bid & 7) * 16) < gen) {
                __builtin_amdgcn_s_sleep(2);
                if (++spins > (1 << 16)) break;
            }
        }
        __syncthreads();
    }
}

// -------------- stage one 512-row + optional stats (m -> scr[8], r -> scr[9])
__device__ __forceinline__ void stage_row(
    float* dst, const float* src, float* scr, int tid, int dostats)
{
    float2 v = cload2(src + tid * 2);
    dst[tid * 2] = v.x; dst[tid * 2 + 1] = v.y;
    if (dostats) {
        float sum = v.x + v.y, sq = v.x * v.x + v.y * v.y;
        #pragma unroll
        for (int off = 32; off; off >>= 1) {
            sum += __shfl_xor(sum, off); sq += __shfl_xor(sq, off);
        }
        if ((tid & 63) == 0) { scr[tid >> 6] = sum; scr[4 + (tid >> 6)] = sq; }
        __syncthreads();
        if (tid == 0) {
            float s = scr[0] + scr[1] + scr[2] + scr[3];
            float q = scr[4] + scr[5] + scr[6] + scr[7];
            float m = s * (1.f / 512.f);
            scr[8] = m; scr[9] = rsqrtf(q * (1.f / 512.f) - m * m + 1e-5f);
        }
    }
    __syncthreads();
}

// -------------- stage 8x512 contiguously + per-row stats (mS/rS)
__device__ __forceinline__ void stage_cs(
    float* dst, const float* src, float* mO, float* rO, float* scr, int tid)
{
    const int wv = tid >> 6, ln = tid & 63;
    float sum[8], sq[8];
    #pragma unroll
    for (int u = 0; u < 8; ++u) {
        float2 v = cload2(src + u * 512 + tid * 2);
        *(float2*)(dst + u * RP + tid * 2) = v;
        sum[u] = v.x + v.y; sq[u] = v.x * v.x + v.y * v.y;
    }
    #pragma unroll
    for (int u = 0; u < 8; ++u) {
        #pragma unroll
        for (int off = 32; off; off >>= 1) {
            sum[u] += __shfl_xor(sum[u], off);
            sq[u]  += __shfl_xor(sq[u], off);
        }
    }
    if (ln == 0) {
        #pragma unroll
        for (int u = 0; u < 8; ++u) {
            scr[u * 4 + wv] = sum[u]; scr[32 + u * 4 + wv] = sq[u];
        }
    }
    __syncthreads();
    if (tid < 8) {
        float s = scr[tid*4] + scr[tid*4+1] + scr[tid*4+2] + scr[tid*4+3];
        float q = scr[32+tid*4] + scr[32+tid*4+1] + scr[32+tid*4+2] + scr[32+tid*4+3];
        float m = s * (1.f / 512.f);
        mO[tid] = m; rO[tid] = rsqrtf(q * (1.f / 512.f) - m * m + 1e-5f);
    }
    __syncthreads();
}

// ------------------------------------------------------------ LDS GEMV pieces
template <int NCOL, int KTOT>
__device__ __forceinline__ void gemv_accum(
    const __half* wcol0, int ldw, int wkoff, const float* xsL, float acc[8], int tid)
{
    constexpr int NKS = 256 / NCOL;
    const int c = tid / NKS, ks = tid % NKS;
    const __half* w = wcol0 + (size_t)c * ldw + wkoff;
    #pragma unroll
    for (int j = 0; j < KTOT / (NKS * 4); ++j) {
        int k = j * (NKS * 4) + ks * 4;
        const __half2* w2 = (const __half2*)(w + k);
        float2 f0 = __half22float2(w2[0]);
        float2 f1 = __half22float2(w2[1]);
        #pragma unroll
        for (int r = 0; r < 8; ++r) {
            const float4 xv = *(const float4*)(xsL + r * RP + k);
            acc[r] += xv.x * f0.x + xv.y * f0.y + xv.z * f1.x + xv.w * f1.y;
        }
    }
}

template <int INLN, int RESLN, int RELU>
__device__ __forceinline__ void emit_one(
    int out_i, float v, int gcol0,
    const float* SGW, const float* BWp,
    const float* mS_, const float* rS_,
    const float* rsL, const float* resg, const float* resb,
    float* out, int outN)
{
    int c2 = out_i >> 3, r = out_i & 7;
    int g = gcol0 + c2;
    if (INLN) v = rS_[r] * (v - mS_[r] * SGW[g]);
    v += BWp[g];
    if (RELU) v = fmaxf(v, 0.f);
    if (RESLN) {
        float rv = rsL[r * RP + g];
        v += (rv - mS_[r]) * rS_[r] * resg[g] + resb[g];
    }
    cstore(out + (size_t)r * outN + g, v);
}

template <int NCOL, int INLN, int RESLN, int RELU>
__device__ __forceinline__ void gemv_finish(
    float acc[8], float* part, int tid, int gcol0,
    const float* SGW, const float* BWp,
    const float* mS_, const float* rS_,
    const float* rsL, const float* resg, const float* resb,
    float* out, int outN)
{
    constexpr int NKS = 256 / NCOL, PP = NKS + 1;
    const int c = tid / NKS, ks = tid % NKS;
    #pragma unroll
    for (int r = 0; r < 8; ++r) part[(c * 8 + r) * PP + ks] = acc[r];
    __syncthreads();
    if (NCOL == 2) {
        int out_i = tid >> 4, t16 = tid & 15;
        float v = 0.f;
        #pragma unroll
        for (int j = 0; j < 8; ++j) v += part[out_i * PP + t16 + 16 * j];
        for (int off = 8; off; off >>= 1) v += __shfl_down(v, off, 16);
        if (t16 == 0)
            emit_one<INLN, RESLN, RELU>(out_i, v, gcol0, SGW, BWp, mS_, rS_,
                                        rsL, resg, resb, out, outN);
    } else {  // NCOL == 8
        int out_i = tid >> 2, t4 = tid & 3;
        float v = 0.f;
        #pragma unroll
        for (int j = 0; j < 8; ++j) v += part[out_i * PP + t4 + 4 * j];
        v += __shfl_down(v, 2, 4); v += __shfl_down(v, 1, 4);
        if (t4 == 0)
            emit_one<INLN, RESLN, RELU>(out_i, v, gcol0, SGW, BWp, mS_, rS_,
                                        rsL, resg, resb, out, outN);
    }
    __syncthreads();
}

// ---------------------------------------------------------------- megakernel
struct MegaParams {
    const float *emb;
    const float *sa_out_b, *ca_out_b, *ffn_b2;
    const float *ln1_g, *ln1_b, *ln2_g, *ln2_b, *ln3_g, *ln3_b;
    const __half *qkvGW16, *saout16, *caq16, *caout16, *ffn116, *ffn216, *clfGW16;
    const float *qkvSGW, *qkvBW, *caqSGW, *caqBW, *ffn1SGW, *ffn1BW, *clfSGW, *clfBW;
    const float *EQ, *PEQ, *peR;
    int *tokens, *flags, *release;
    float *Kmem, *Vmem, *Ksa0, *Vsa0;
    float *qbuf, *y1acc, *y2acc, *hb, *y3, *x0buf;
    float *out_logits, *out_sampled;
};

__device__ __forceinline__ void cp16(__half* dst, const __half* src, int halfs, int tid) {
    const int4* s = (const int4*)src;
    int4* d = (int4*)dst;
    int n = halfs >> 3;
    for (int i = tid; i < n; i += 256) d[i] = s[i];
}

__global__ __launch_bounds__(256, 1) void mega_kernel(MegaParams p) {
    __shared__ __align__(16) __half wff[WTOT];        // 49.6 KB: ffn1+ffn2
    __shared__ float kvK[NLAYER * LLEN * KVP];        // 25.3 KB
    __shared__ float kvV[NLAYER * LLEN * KVP];        // 25.3 KB
    __shared__ float rs[BB * RP];                     // 16.6 KB
    __shared__ float xs[BB * RP];                     // 16.6 KB
    __shared__ float part[2112];                      // 8.4 KB
    __shared__ float scr[64];
    __shared__ float qsh[64];
    __shared__ float mS[8], rS[8];
    __shared__ int   tokLDS;
    __shared__ float argv[2];
    __shared__ int   argi[2];
    const int tid = threadIdx.x, bid = blockIdx.x;
    const int ab = bid >> 3, ah = bid & 7;   // attention block coords (bid<64)
    int g = 0;

    // ---- one-time LDS fill: ffn weights ----
    for (int l = 0; l < NLAYER; ++l) {
        cp16(wff + OFF_FFN1 + l * 4160, p.ffn116 + ((size_t)l * 2048 + bid * 8) * WLD, 8 * WLD, tid);
        cp16(wff + OFF_FFN2 + l * 4112, p.ffn216 + ((size_t)l * 512 + bid * 2) * WLD2, 2 * WLD2, tid);
    }
    __syncthreads();

    for (int t = 0; t < LLEN; ++t) {
        for (int l = 0; l < NLAYER; ++l) {
            // ======== PA: [qkv +] self-attn + saout-fold (64 blocks) ========
            if (bid < 64) {
                const int b = ab, h = ah;
                if (l == 0) {
                    stage_row(rs, p.x0buf + b * DD, scr, tid, 0);  // raw residual
                    if (tid < 64) qsh[tid] = cload(p.qbuf + b * DD + h * HDIM + tid);
                    else if (tid < 128)
                        kvK[t * KVP + (tid - 64)] =
                            cload(p.Ksa0 + ((size_t)b * LLEN + t) * DD + h * HDIM + (tid - 64));
                    else if (tid < 192)
                        kvV[t * KVP + (tid - 128)] =
                            cload(p.Vsa0 + ((size_t)b * LLEN + t) * DD + h * HDIM + (tid - 128));
                    __syncthreads();
                } else {
                    stage_row(rs, p.y3 + b * DD, scr, tid, 1);     // LN3 stats
                    const float m0 = scr[8], r0 = scr[9];
                    // qkv GEMV: 3 mats x 64 cols, 4-way k-split
                    const int c = tid & 63, ks = tid >> 6;
                    #pragma unroll
                    for (int m = 0; m < 3; ++m) {
                        const __half2* w2 = (const __half2*)(p.qkvGW16 +
                            ((size_t)((l - 1) * 1536 + m * 512 + h * HDIM + c)) * WLD + ks * 128);
                        const float* x0 = rs + ks * 128;
                        float a = 0.f;
                        #pragma unroll 16
                        for (int i2 = 0; i2 < 64; ++i2) {
                            float2 f = __half22float2(w2[i2]);
                            a += x0[2 * i2] * f.x + x0[2 * i2 + 1] * f.y;
                        }
                        part[m * 256 + ks * 64 + c] = a;
                    }
                    __syncthreads();
                    if (tid < 192) {
                        int m = tid >> 6, c2 = tid & 63;
                        float raw = part[m * 256 + c2] + part[m * 256 + 64 + c2]
                                  + part[m * 256 + 128 + c2] + part[m * 256 + 192 + c2];
                        int gc = (l - 1) * 1536 + m * 512 + h * HDIM + c2;
                        float val = r0 * (raw - m0 * p.qkvSGW[gc]) + p.qkvBW[gc];
                        if (m == 0)      qsh[c2] = val;
                        else if (m == 1) kvK[(l * LLEN + t) * KVP + c2] = val;
                        else             kvV[(l * LLEN + t) * KVP + c2] = val;
                    }
                    __syncthreads();
                }
                // ---- self-attn over LDS KV ----
                if (tid <= t) {
                    const float* kr = kvK + (l * LLEN + tid) * KVP;
                    float s = 0.f;
                    #pragma unroll 16
                    for (int d = 0; d < HDIM; ++d) s += qsh[d] * kr[d];
                    part[tid] = s * 0.125f;
                }
                __syncthreads();
                if (tid < 64) {
                    float s = (tid <= t) ? part[tid] : -1e30f;
                    float mx = s;
                    for (int off = 32; off; off >>= 1) mx = fmaxf(mx, __shfl_xor(mx, off));
                    float pe = (tid <= t) ? expf(s - mx) : 0.f;
                    float sum = pe;
                    for (int off = 32; off; off >>= 1) sum += __shfl_xor(sum, off);
                    if (tid <= t) part[tid] = pe / sum;
                }
                __syncthreads();
                if (tid < 64) {
                    float o = 0.f;
                    for (int j = 0; j <= t; ++j) o += part[j] * kvV[(l * LLEN + j) * KVP + tid];
                    part[64 + tid] = o;
                }
                __syncthreads();
                // ---- saout contribution: 2 cols/thread, atomicAdd into y1acc ----
                {
                    const int c0 = tid * 2;
                    const float m0 = scr[8], r0 = scr[9];
                    const __half* w0 = p.saout16 + ((size_t)(l * 512 + c0)) * WLD + h * HDIM;
                    const __half* w1 = w0 + WLD;
                    float a0 = 0.f, a1 = 0.f;
                    #pragma unroll 16
                    for (int d = 0; d < HDIM; ++d) {
                        float pv = part[64 + d];
                        a0 += pv * __half2float(w0[d]);
                        a1 += pv * __half2float(w1[d]);
                    }
                    if (h == 0) {
                        float x0r = rs[c0], x1r = rs[c0 + 1];
                        if (l > 0) {
                            x0r = (x0r - m0) * r0 * p.ln3_g[(l - 1) * DD + c0] + p.ln3_b[(l - 1) * DD + c0];
                            x1r = (x1r - m0) * r0 * p.ln3_g[(l - 1) * DD + c0 + 1] + p.ln3_b[(l - 1) * DD + c0 + 1];
                        }
                        a0 += p.sa_out_b[l * DD + c0] + x0r;
                        a1 += p.sa_out_b[l * DD + c0 + 1] + x1r;
                    }
                    atomicAdd(p.y1acc + b * DD + c0, a0);
                    atomicAdd(p.y1acc + b * DD + c0 + 1, a1);
                }
            } else if (bid < 72) {
                // zero y2acc for this layer's cross-attn accumulation
                cstore(p.y2acc + (bid - 64) * DD + tid * 2, 0.f);
                cstore(p.y2acc + (bid - 64) * DD + tid * 2 + 1, 0.f);
            }
            gbar(p.flags, p.release, ++g, bid, tid);

            // ======== PB: caq-fold + cross-attn + caout-fold (64 blocks) ========
            if (bid < 64) {
                const int b = ab, h = ah;
                stage_row(rs, p.y1acc + b * DD, scr, tid, 1);      // LN1 stats
                const float m0 = scr[8], r0 = scr[9];
                // caq folded GEMV: 64 cols, 4-way k-split
                {
                    const int c = tid & 63, ks = tid >> 6;
                    const __half2* w2 = (const __half2*)(p.caq16 +
                        ((size_t)(l * 512 + h * HDIM + c)) * WLD + ks * 128);
                    const float* x0 = rs + ks * 128;
                    float a = 0.f;
                    #pragma unroll 16
                    for (int i2 = 0; i2 < 64; ++i2) {
                        float2 f = __half22float2(w2[i2]);
                        a += x0[2 * i2] * f.x + x0[2 * i2 + 1] * f.y;
                    }
                    part[ks * 64 + c] = a;
                }
                __syncthreads();
                if (tid < 64) {
                    float raw = part[tid] + part[64 + tid] + part[128 + tid] + part[192 + tid];
                    int gc = l * 512 + h * HDIM + tid;
                    qsh[tid] = r0 * (raw - m0 * p.caqSGW[gc]) + p.caqBW[gc];
                }
                __syncthreads();
                // scores vs Kmem (fp32, L2-hot)
                float* sc = part + 256;   // 128 scores
                if (tid < 128) {
                    const float* kp = p.Kmem + (((size_t)(l * 8 + b)) * SMEMN + tid) * DD + h * HDIM;
                    float s = 0.f;
                    #pragma unroll 8
                    for (int d = 0; d < HDIM; ++d) s += qsh[d] * kp[d];
                    sc[tid] = s * 0.125f;
                }
                __syncthreads();
                if (tid < 64) {
                    float s0 = sc[tid], s1 = sc[tid + 64];
                    float mx = fmaxf(s0, s1);
                    for (int off = 32; off; off >>= 1) mx = fmaxf(mx, __shfl_xor(mx, off));
                    float e0 = expf(s0 - mx), e1 = expf(s1 - mx);
                    float sum = e0 + e1;
                    for (int off = 32; off; off >>= 1) sum += __shfl_xor(sum, off);
                    sc[tid] = e0 / sum; sc[tid + 64] = e1 / sum;
                }
                __syncthreads();
                float* po = part + 384;  // 128 partials
                if (tid < 128) {
                    int d = tid & 63, half = tid >> 6;
                    const float* Vb = p.Vmem + (((size_t)(l * 8 + b)) * SMEMN + half * 64) * DD + h * HDIM + d;
                    float o = 0.f;
                    for (int j = 0; j < 64; ++j) o += sc[half * 64 + j] * Vb[(size_t)j * DD];
                    po[half * 64 + d] = o;
                }
                __syncthreads();
                if (tid < 64) part[512 + tid] = po[tid] + po[64 + tid];   // cat_h
                __syncthreads();
                // caout contribution
                {
                    const int c0 = tid * 2;
                    const __half* w0 = p.caout16 + ((size_t)(l * 512 + c0)) * WLD + h * HDIM;
                    const __half* w1 = w0 + WLD;
                    float a0 = 0.f, a1 = 0.f;
                    #pragma unroll 16
                    for (int d = 0; d < HDIM; ++d) {
                        float cv = part[512 + d];
                        a0 += cv * __half2float(w0[d]);
                        a1 += cv * __half2float(w1[d]);
                    }
                    if (h == 0) {
                        float r0v = (rs[c0] - m0) * r0 * p.ln1_g[l * DD + c0] + p.ln1_b[l * DD + c0];
                        float r1v = (rs[c0 + 1] - m0) * r0 * p.ln1_g[l * DD + c0 + 1] + p.ln1_b[l * DD + c0 + 1];
                        a0 += p.ca_out_b[l * DD + c0] + r0v;
                        a1 += p.ca_out_b[l * DD + c0 + 1] + r1v;
                    }
                    atomicAdd(p.y2acc + b * DD + c0, a0);
                    atomicAdd(p.y2acc + b * DD + c0 + 1, a1);
                }
            }
            gbar(p.flags, p.release, ++g, bid, tid);

            // ======== PC: ffn1 (256 blocks, LN2-folded, relu) ========
            {
                stage_cs(rs, p.y2acc, mS, rS, scr, tid);
                float acc[8] = {};
                gemv_accum<8, 512>(wff + OFF_FFN1 + l * 4160, WLD, 0, rs, acc, tid);
                gemv_finish<8, 1, 0, 1>(acc, part, tid, bid * 8,
                    p.ffn1SGW + l * DFFN, p.ffn1BW + l * DFFN, mS, rS,
                    nullptr, nullptr, nullptr, p.hb, DFFN);
                if (bid >= 240)  // zero y1acc for next layer/step
                    cstore(p.y1acc + (bid - 240) * 256 + tid, 0.f);
            }
            gbar(p.flags, p.release, ++g, bid, tid);

            // ======== PD: ffn2 (256 blocks, K=2048 in 4 chunks) + LN2 residual ========
            {
                float acc[8] = {};
                #pragma unroll
                for (int ch = 0; ch < 4; ++ch) {
                    #pragma unroll
                    for (int u = 0; u < 8; ++u) {
                        float2 v = cload2(p.hb + u * DFFN + ch * 512 + tid * 2);
                        *(float2*)(xs + u * RP + tid * 2) = v;
                    }
                    __syncthreads();
                    gemv_accum<2, 512>(wff + OFF_FFN2 + l * 4112, WLD2, ch * 512, xs, acc, tid);
                    __syncthreads();
                }
                gemv_finish<2, 0, 1, 0>(acc, part, tid, bid * 2,
                    nullptr, p.ffn_b2 + l * DD, mS, rS,
                    rs, p.ln2_g + l * DD, p.ln2_b + l * DD, p.y3, DD);
            }
            gbar(p.flags, p.release, ++g, bid, tid);
        }

        // ======== CLF: LN3-folded logits + argmax + next-step qkv0/x0 (8 blocks) ========
        if (bid < 8) {
            const int b = bid;
            stage_row(rs, p.y3 + b * DD, scr, tid, 1);
            {
                int cl = tid & 127, kh = tid >> 7;
                const __half2* w2 = (const __half2*)(p.clfGW16 + (size_t)cl * 512 + kh * 256);
                const float* xh = rs + kh * 256;
                float lg = 0.f;
                #pragma unroll 8
                for (int k2 = 0; k2 < 128; ++k2) {
                    float2 f = __half22float2(w2[k2]);
                    lg += xh[2 * k2] * f.x + xh[2 * k2 + 1] * f.y;
                }
                part[tid] = lg;
            }
            __syncthreads();
            if (tid < 128) {
                float m = scr[8], ri = scr[9];
                float lg = ri * ((part[tid] + part[128 + tid]) - m * p.clfSGW[tid]) + p.clfBW[tid];
                p.out_logits[((size_t)b * LLEN + t) * VV + tid] = lg;
                float bv = lg; int bi = tid;
                for (int off = 32; off; off >>= 1) {
                    float ov = __shfl_xor(bv, off); int oi = __shfl_xor(bi, off);
                    if (ov > bv || (ov == bv && oi < bi)) { bv = ov; bi = oi; }
                }
                if ((tid & 63) == 0) { argv[tid >> 6] = bv; argi[tid >> 6] = bi; }
            }
            __syncthreads();
            if (tid == 0) {
                int best = (argv[1] > argv[0] || (argv[1] == argv[0] && argi[1] < argi[0]))
                               ? argi[1] : argi[0];
                icstore(p.tokens + b * (LLEN + 1) + t + 1, best);
                tokLDS = best;
            }
            __syncthreads();
            if (t < LLEN - 1) {
                int tok = tokLDS, tn = t + 1;
                for (int c = tid; c < 3 * DD; c += 256) {
                    float v = p.EQ[(size_t)tok * (3 * DD) + c] + p.PEQ[(size_t)tn * (3 * DD) + c];
                    if (c < DD)          cstore(p.qbuf + b * DD + c, v);
                    else if (c < 2 * DD) cstore(p.Ksa0 + ((size_t)b * LLEN + tn) * DD + (c - DD), v);
                    else                 cstore(p.Vsa0 + ((size_t)b * LLEN + tn) * DD + (c - 2 * DD), v);
                }
                for (int c = tid; c < DD; c += 256)
                    cstore(p.x0buf + b * DD + c,
                           p.emb[(size_t)tok * DD + c] * EMB_SCALE + p.peR[(size_t)tn * DD + c]);
            }
        }
        gbar(p.flags, p.release, ++g, bid, tid);
    }

    // ---- finalize sampled ----
    if (bid == 0 && tid < BB) {
        int b = tid;
        int toks[LLEN + 1];
        for (int j = 0; j <= LLEN; j++) toks[j] = icload(p.tokens + b * (LLEN + 1) + j);
        int eos = 0;
        for (int j = 1; j <= LLEN; j++)
            if (toks[j] == EOS_T) { eos = j; break; }
        for (int j = 0; j <= LLEN; j++) {
            int v = toks[j];
            if (eos != 0 && j > eos + 1) v = PAD_T;
            p.out_sampled[b * (LLEN + 1) + j] = (float)v;
        }
    }
}

// --------------------------------------------------------------------- host
extern "C" void kernel_launch(void* const* d_in, const int* in_sizes, int n_in,
                              void* d_out, int out_size, void* d_ws, size_t ws_size,
                              hipStream_t stream) {
    const float* memory   = (const float*)d_in[0];
    const float* emb      = (const float*)d_in[1];
    const float* sa_qkv_w = (const float*)d_in[2];
    const float* sa_qkv_b = (const float*)d_in[3];
    const float* sa_out_w = (const float*)d_in[4];
    const float* sa_out_b = (const float*)d_in[5];
    const float* ca_q_w   = (const float*)d_in[6];
    const float* ca_q_b   = (const float*)d_in[7];
    const float* ca_kv_w  = (const float*)d_in[8];
    const float* ca_kv_b  = (const float*)d_in[9];
    const float* ca_out_w = (const float*)d_in[10];
    const float* ca_out_b = (const float*)d_in[11];
    const float* ln1_g    = (const float*)d_in[12];
    const float* ln1_b    = (const float*)d_in[13];
    const float* ln2_g    = (const float*)d_in[14];
    const float* ln2_b    = (const float*)d_in[15];
    const float* ln3_g    = (const float*)d_in[16];
    const float* ln3_b    = (const float*)d_in[17];
    const float* ffn_w1   = (const float*)d_in[18];
    const float* ffn_b1   = (const float*)d_in[19];
    const float* ffn_w2   = (const float*)d_in[20];
    const float* ffn_b2   = (const float*)d_in[21];
    const float* clf_w    = (const float*)d_in[22];
    const float* clf_b    = (const float*)d_in[23];

    float* f   = (float*)d_ws;
    int*   wsI = (int*)d_ws;
    int* flags   = wsI;                       // 4096 ints
    int* release = wsI + 4096;                // 128 ints
    int* tokens  = wsI + 4224;                // 264 ints
    float* y1acc = f + 4488;                  // 4096
    float* y2acc = f + 8584;                  // 4096
    float* peR   = f + 12800;                 // 16384
    float* Kmem  = peR + LLEN * DD;
    float* Vmem  = Kmem + (size_t)NLAYER * BB * SMEMN * DD;
    float* Ksa0  = Vmem + (size_t)NLAYER * BB * SMEMN * DD;   // 8*32*512
    float* Vsa0  = Ksa0 + (size_t)BB * LLEN * DD;
    float* qbuf  = Vsa0 + (size_t)BB * LLEN * DD;
    float* hb    = qbuf + BB * DD;
    float* y3    = hb + BB * DFFN;
    float* x0buf = y3 + BB * DD;
    float* EQ    = x0buf + BB * DD;
    float* PEQ   = EQ + (size_t)VV * 3 * DD;
    float* qkvSGW = PEQ + (size_t)LLEN * 3 * DD;
    float* qkvBW  = qkvSGW + 2 * 1536;
    float* caqSGW = qkvBW + 2 * 1536;
    float* caqBW  = caqSGW + 3 * 512;
    float* ffn1SGW = caqBW + 3 * 512;
    float* ffn1BW  = ffn1SGW + 3 * 2048;
    float* clfSGW  = ffn1BW + 3 * 2048;
    float* clfBW   = clfSGW + 128;
    __half* qkvGW16 = (__half*)(clfBW + 128);
    __half* saout16 = qkvGW16 + (size_t)2 * 1536 * WLD;
    __half* caq16   = saout16 + (size_t)3 * 512 * WLD;
    __half* caout16 = caq16   + (size_t)3 * 512 * WLD;
    __half* ffn116  = caout16 + (size_t)3 * 512 * WLD;
    __half* ffn216  = ffn116  + (size_t)3 * 2048 * WLD;
    __half* clfGW16 = ffn216  + (size_t)3 * 512 * WLD2;

    float* out_logits  = (float*)d_out;
    float* out_sampled = out_logits + (size_t)BB * LLEN * VV;

    hipMemsetAsync(d_ws, 0, 50720, stream);   // flags+release+tokens+y1acc+y2acc
    k_init<<<1, 512, 0, stream>>>(tokens, peR);

    t16pad<<<dim3(16, 48, 2), 256, 0, stream>>>(sa_qkv_w + (size_t)512 * 1536, ln3_g, qkvGW16, 512, 1536, WLD);
    t16pad<<<dim3(16, 16, 3), 256, 0, stream>>>(sa_out_w, nullptr, saout16, 512, 512, WLD);
    t16pad<<<dim3(16, 16, 3), 256, 0, stream>>>(ca_q_w,   ln1_g,   caq16,   512, 512, WLD);
    t16pad<<<dim3(16, 16, 3), 256, 0, stream>>>(ca_out_w, nullptr, caout16, 512, 512, WLD);
    t16pad<<<dim3(16, 64, 3), 256, 0, stream>>>(ffn_w1,   ln2_g,   ffn116,  512, 2048, WLD);
    t16pad<<<dim3(64, 16, 3), 256, 0, stream>>>(ffn_w2,   nullptr, ffn216,  2048, 512, WLD2);
    t16pad<<<dim3(16, 4, 1),  256, 0, stream>>>(clf_w,    ln3_g + 2 * 512, clfGW16, 512, 128, 512);

    k_colvec<<<dim3(6, 2), 256, 0, stream>>>(sa_qkv_w + (size_t)512 * 1536, ln3_g, ln3_b,
                                             sa_qkv_b + 1536, qkvSGW, qkvBW, 512, 1536);
    k_colvec<<<dim3(2, 3), 256, 0, stream>>>(ca_q_w, ln1_g, ln1_b, ca_q_b, caqSGW, caqBW, 512, 512);
    k_colvec<<<dim3(8, 3), 256, 0, stream>>>(ffn_w1, ln2_g, ln2_b, ffn_b1, ffn1SGW, ffn1BW, 512, 2048);
    k_colvec<<<dim3(1, 1), 256, 0, stream>>>(clf_w, ln3_g + 1024, ln3_b + 1024, clf_b,
                                             clfSGW, clfBW, 512, 128);

    k_eqpeq<<<VV + LLEN, 256, 0, stream>>>(emb, peR, sa_qkv_w, sa_qkv_b, EQ, PEQ);
    memkv_kernel<<<dim3(16, 16, 3), 256, 0, stream>>>(memory, ca_kv_w, ca_kv_b, Kmem, Vmem);
    k_seed<<<8, 256, 0, stream>>>(EQ, PEQ, emb, peR, qbuf, Ksa0, Vsa0, x0buf);

    MegaParams p;
    p.emb = emb;
    p.sa_out_b = sa_out_b; p.ca_out_b = ca_out_b; p.ffn_b2 = ffn_b2;
    p.ln1_g = ln1_g; p.ln1_b = ln1_b;
    p.ln2_g = ln2_g; p.ln2_b = ln2_b;
    p.ln3_g = ln3_g; p.ln3_b = ln3_b;
    p.qkvGW16 = qkvGW16; p.saout16 = saout16; p.caq16 = caq16; p.caout16 = caout16;
    p.ffn116 = ffn116; p.ffn216 = ffn216; p.clfGW16 = clfGW16;
    p.qkvSGW = qkvSGW; p.qkvBW = qkvBW; p.caqSGW = caqSGW; p.caqBW = caqBW;
    p.ffn1SGW = ffn1SGW; p.ffn1BW = ffn1BW; p.clfSGW = clfSGW; p.clfBW = clfBW;
    p.EQ = EQ; p.PEQ = PEQ; p.peR = peR;
    p.tokens = tokens; p.flags = flags; p.release = release;
    p.Kmem = Kmem; p.Vmem = Vmem; p.Ksa0 = Ksa0; p.Vsa0 = Vsa0;
    p.qbuf = qbuf; p.y1acc = y1acc; p.y2acc = y2acc;
    p.hb = hb; p.y3 = y3; p.x0buf = x0buf;
    p.out_logits = out_logits; p.out_sampled = out_sampled;

    mega_kernel<<<NB, 256, 0, stream>>>(p);
}

// Round 9
// 5175.229 us; speedup vs baseline: 1.5445x; 1.1567x over previous
//
#include <hip/hip_runtime.h>
#include <hip/hip_fp16.h>
#include <math.h>

#define BB 8
#define SMEMN 128
#define DD 512
#define HDIM 64
#define DFFN 2048
#define NLAYER 3
#define VV 128
#define LLEN 32
#define SOS_T 1
#define EOS_T 2
#define PAD_T 0
#define NB 256
#define RP 520           // activation row pitch (floats)
#define WLD 520          // weight col pitch (halfs), K=512 mats
#define WLD2 2056        // ffn2 col pitch (halfs), K=2048
#define KVP 66           // LDS KV row pitch (floats)
#define EMB_SCALE 22.62741699796952f

// LDS-resident weights: ffn1 + ffn2 only
#define OFF_FFN1  0          // 3 layers x 8 cols x 520
#define OFF_FFN2  12480      // 3 layers x 2 cols x 2056
#define WTOT      24816

// ---- agent-scope (sc1) accessors
__device__ __forceinline__ float cload(const float* p) {
    return __hip_atomic_load(p, __ATOMIC_RELAXED, __HIP_MEMORY_SCOPE_AGENT);
}
__device__ __forceinline__ float2 cload2(const float* p) {
    unsigned long long u = __hip_atomic_load((const unsigned long long*)p,
                                             __ATOMIC_RELAXED, __HIP_MEMORY_SCOPE_AGENT);
    union { unsigned long long u; float2 f; } c; c.u = u; return c.f;
}
__device__ __forceinline__ void cstore(float* p, float v) {
    __hip_atomic_store(p, v, __ATOMIC_RELAXED, __HIP_MEMORY_SCOPE_AGENT);
}
__device__ __forceinline__ int icload(const int* p) {
    return __hip_atomic_load(p, __ATOMIC_RELAXED, __HIP_MEMORY_SCOPE_AGENT);
}
__device__ __forceinline__ void icstore(int* p, int v) {
    __hip_atomic_store(p, v, __ATOMIC_RELAXED, __HIP_MEMORY_SCOPE_AGENT);
}

// ================================================================ prologue
struct ProParams {
    const float *memory, *emb;
    const float *sa_qkv_w, *sa_qkv_b, *sa_out_w;
    const float *ca_q_w, *ca_q_b, *ca_kv_w, *ca_kv_b, *ca_out_w;
    const float *ln1_g, *ln1_b, *ln2_g, *ln2_b, *ln3_g, *ln3_b;
    const float *ffn_w1, *ffn_b1, *ffn_w2, *clf_w, *clf_b;
    int* tokens;
    float *peR, *Kmem, *Vmem, *EQ, *PEQ;
    float *qkvSGW, *qkvBW, *caqSGW, *caqBW, *ffn1SGW, *ffn1BW, *clfSGW, *clfBW;
    __half *qkvGW16, *saout16, *caq16, *caout16, *ffn116, *ffn216, *clfGW16;
};

__device__ void dev_t16pad(int bl, const float* src, const float* g, __half* dst,
                           int K, int N, int KPAD, float* tile, int tid) {
    // tile used as [32][33]
    int nbx = K >> 5, nby = N >> 5;
    int bx = bl % nbx; int rest = bl / nbx;
    int by = rest % nby; int z = rest / nby;
    int k0 = bx * 32, n0 = by * 32;
    const float* s = src + (size_t)z * K * N;
    __half* d = dst + (size_t)z * N * KPAD;
    int r = tid >> 5, c = tid & 31;
    #pragma unroll
    for (int i = 0; i < 4; i++) {
        int kk = k0 + r + i * 8;
        float gv = g ? g[(size_t)z * K + kk] : 1.f;
        tile[(r + i * 8) * 33 + c] = s[(size_t)kk * N + n0 + c] * gv;
    }
    __syncthreads();
    #pragma unroll
    for (int i = 0; i < 4; i++)
        d[(size_t)(n0 + r + i * 8) * KPAD + k0 + c] = (__half)tile[c * 33 + r + i * 8];
}

__device__ void dev_colvec(int bl, int nx, const float* W, const float* g, const float* b,
                           const float* bias, float* SGW, float* BW, int K, int N, int tid) {
    int bx = bl % nx, z = bl / nx;
    int c = bx * 256 + tid;
    if (c >= N) return;
    const float* Wz = W + (size_t)z * K * N;
    float sg = 0.f, bw = 0.f;
    for (int k = 0; k < K; ++k) {
        float w = Wz[(size_t)k * N + c];
        sg += g[(size_t)z * K + k] * w;
        bw += b[(size_t)z * K + k] * w;
    }
    SGW[(size_t)z * N + c] = sg;
    BW[(size_t)z * N + c] = bw + bias[(size_t)z * N + c];
}

__device__ void dev_eqpeq(int row, const float* emb, const float* W0, const float* b0,
                          float* EQ, float* PEQ, float* x, int tid) {
    bool isE = row < VV;
    for (int k = tid; k < DD; k += 256) {
        if (isE) x[k] = emb[(size_t)row * DD + k] * EMB_SCALE;
        else {
            int tt = row - VV;
            int pos = (tt == 0) ? 0 : (tt + 1);
            float freq = expf((float)(k & ~1) * (-9.210340371976184f / 512.f));
            float ang = (float)pos * freq;
            x[k] = (k & 1) ? cosf(ang) : sinf(ang);
        }
    }
    __syncthreads();
    for (int c = tid; c < 3 * DD; c += 256) {
        float a = isE ? b0[c] : 0.f;
        for (int k = 0; k < DD; ++k) a += x[k] * W0[(size_t)k * (3 * DD) + c];
        if (isE) EQ[(size_t)row * (3 * DD) + c] = a;
        else     PEQ[(size_t)(row - VV) * (3 * DD) + c] = a;
    }
}

__device__ void dev_memkv(int bl, const float* mem, const float* Wkv, const float* bkv,
                          float* Kmem, float* Vmem, float* smem, int tid) {
    float* As = smem;          // [64][20]
    float* Bs = smem + 1280;   // [16][68]
    int bx = bl & 15, by = (bl >> 4) & 15, l = bl >> 8;
    const float* Wl = Wkv + (size_t)l * DD * (2 * DD);
    const float* bl_ = bkv + l * (2 * DD);
    int brow = by * 64, bcol = bx * 64;
    int ty = tid / 16, tx = tid % 16;
    float acc[4][4] = {};
    for (int k0 = 0; k0 < DD; k0 += 16) {
        {
            int r = tid >> 2, kk = (tid & 3) * 4;
            const float4 av = *(const float4*)(mem + (size_t)(brow + r) * DD + k0 + kk);
            As[r * 20 + kk] = av.x; As[r * 20 + kk + 1] = av.y;
            As[r * 20 + kk + 2] = av.z; As[r * 20 + kk + 3] = av.w;
        }
        {
            int kb = tid >> 4, j = (tid & 15) * 4;
            const float4 bv = *(const float4*)(Wl + (size_t)(k0 + kb) * (2 * DD) + bcol + j);
            Bs[kb * 68 + j] = bv.x; Bs[kb * 68 + j + 1] = bv.y;
            Bs[kb * 68 + j + 2] = bv.z; Bs[kb * 68 + j + 3] = bv.w;
        }
        __syncthreads();
        #pragma unroll
        for (int kk2 = 0; kk2 < 16; kk2++) {
            float a0 = As[(ty * 4 + 0) * 20 + kk2], a1 = As[(ty * 4 + 1) * 20 + kk2];
            float a2 = As[(ty * 4 + 2) * 20 + kk2], a3 = As[(ty * 4 + 3) * 20 + kk2];
            float b0 = Bs[kk2 * 68 + tx * 4 + 0], b1 = Bs[kk2 * 68 + tx * 4 + 1];
            float b2 = Bs[kk2 * 68 + tx * 4 + 2], b3 = Bs[kk2 * 68 + tx * 4 + 3];
            acc[0][0] += a0 * b0; acc[0][1] += a0 * b1; acc[0][2] += a0 * b2; acc[0][3] += a0 * b3;
            acc[1][0] += a1 * b0; acc[1][1] += a1 * b1; acc[1][2] += a1 * b2; acc[1][3] += a1 * b3;
            acc[2][0] += a2 * b0; acc[2][1] += a2 * b1; acc[2][2] += a2 * b2; acc[2][3] += a2 * b3;
            acc[3][0] += a3 * b0; acc[3][1] += a3 * b1; acc[3][2] += a3 * b2; acc[3][3] += a3 * b3;
        }
        __syncthreads();
    }
    for (int i = 0; i < 4; i++)
        for (int j = 0; j < 4; j++) {
            int row = brow + ty * 4 + i, colg = bcol + tx * 4 + j;
            float v = acc[i][j] + bl_[colg];
            if (colg < DD) Kmem[((size_t)l * (BB * SMEMN) + row) * DD + colg] = v;
            else           Vmem[((size_t)l * (BB * SMEMN) + row) * DD + (colg - DD)] = v;
        }
}

__device__ void dev_init(int* tokens, float* peR, int tid) {
    for (int i = tid; i < BB * (LLEN + 1); i += 256)
        tokens[i] = (i % (LLEN + 1) == 0) ? SOS_T : PAD_T;
    for (int idx = tid; idx < LLEN * DD; idx += 256) {
        int t = idx >> 9, d = idx & 511;
        int pos = (t == 0) ? 0 : (t + 1);
        float freq = expf((float)(d & ~1) * (-9.210340371976184f / 512.f));
        float ang = (float)pos * freq;
        peR[idx] = (d & 1) ? cosf(ang) : sinf(ang);
    }
}

__global__ __launch_bounds__(256) void k_prologue(ProParams q) {
    __shared__ float smem[2432];
    const int tid = threadIdx.x;
    int bl = blockIdx.x;
    if (bl < 1536) {
        dev_t16pad(bl, q.sa_qkv_w + (size_t)512 * 1536, q.ln3_g, q.qkvGW16, 512, 1536, WLD, smem, tid);
    } else if ((bl -= 1536) < 768) {
        dev_t16pad(bl, q.sa_out_w, nullptr, q.saout16, 512, 512, WLD, smem, tid);
    } else if ((bl -= 768) < 768) {
        dev_t16pad(bl, q.ca_q_w, q.ln1_g, q.caq16, 512, 512, WLD, smem, tid);
    } else if ((bl -= 768) < 768) {
        dev_t16pad(bl, q.ca_out_w, nullptr, q.caout16, 512, 512, WLD, smem, tid);
    } else if ((bl -= 768) < 3072) {
        dev_t16pad(bl, q.ffn_w1, q.ln2_g, q.ffn116, 512, 2048, WLD, smem, tid);
    } else if ((bl -= 3072) < 3072) {
        dev_t16pad(bl, q.ffn_w2, nullptr, q.ffn216, 2048, 512, WLD2, smem, tid);
    } else if ((bl -= 3072) < 64) {
        dev_t16pad(bl, q.clf_w, q.ln3_g + 2 * 512, q.clfGW16, 512, 128, 512, smem, tid);
    } else if ((bl -= 64) < 12) {
        dev_colvec(bl, 6, q.sa_qkv_w + (size_t)512 * 1536, q.ln3_g, q.ln3_b,
                   q.sa_qkv_b + 1536, q.qkvSGW, q.qkvBW, 512, 1536, tid);
    } else if ((bl -= 12) < 6) {
        dev_colvec(bl, 2, q.ca_q_w, q.ln1_g, q.ln1_b, q.ca_q_b, q.caqSGW, q.caqBW, 512, 512, tid);
    } else if ((bl -= 6) < 24) {
        dev_colvec(bl, 8, q.ffn_w1, q.ln2_g, q.ln2_b, q.ffn_b1, q.ffn1SGW, q.ffn1BW, 512, 2048, tid);
    } else if ((bl -= 24) < 1) {
        dev_colvec(0, 1, q.clf_w, q.ln3_g + 1024, q.ln3_b + 1024, q.clf_b,
                   q.clfSGW, q.clfBW, 512, 128, tid);
    } else if ((bl -= 1) < 160) {
        dev_eqpeq(bl, q.emb, q.sa_qkv_w, q.sa_qkv_b, q.EQ, q.PEQ, smem, tid);
    } else if ((bl -= 160) < 768) {
        dev_memkv(bl, q.memory, q.ca_kv_w, q.ca_kv_b, q.Kmem, q.Vmem, smem, tid);
    } else {
        dev_init(q.tokens, q.peR, tid);
    }
}

// ----------------------------- relay grid barrier
__device__ __forceinline__ void gbar(int* flags, int* release, int gen, int bid, int tid) {
    asm volatile("s_waitcnt vmcnt(0)" ::: "memory");
    __syncthreads();
    if (bid == 0) {
        if (tid > 0) {
            int spins = 0;
            while (icload(flags + tid * 16) < gen) {
                __builtin_amdgcn_s_sleep(1);
                if (++spins > (1 << 16)) break;
            }
        }
        __syncthreads();
        if (tid < 8) icstore(release + tid * 16, gen);
    } else {
        if (tid == 0) {
            icstore(flags + bid * 16, gen);
            int spins = 0;
            while (icload(release + (bid & 7) * 16) < gen) {
                __builtin_amdgcn_s_sleep(2);
                if (++spins > (1 << 16)) break;
            }
        }
        __syncthreads();
    }
}

// -------------- stage one 512-row + optional stats (m -> scr[8], r -> scr[9])
__device__ __forceinline__ void stage_row(
    float* dst, const float* src, float* scr, int tid, int dostats)
{
    float2 v = cload2(src + tid * 2);
    dst[tid * 2] = v.x; dst[tid * 2 + 1] = v.y;
    if (dostats) {
        float sum = v.x + v.y, sq = v.x * v.x + v.y * v.y;
        #pragma unroll
        for (int off = 32; off; off >>= 1) {
            sum += __shfl_xor(sum, off); sq += __shfl_xor(sq, off);
        }
        if ((tid & 63) == 0) { scr[tid >> 6] = sum; scr[4 + (tid >> 6)] = sq; }
        __syncthreads();
        if (tid == 0) {
            float s = scr[0] + scr[1] + scr[2] + scr[3];
            float q = scr[4] + scr[5] + scr[6] + scr[7];
            float m = s * (1.f / 512.f);
            scr[8] = m; scr[9] = rsqrtf(q * (1.f / 512.f) - m * m + 1e-5f);
        }
    }
    __syncthreads();
}

// -------------- stage 8x512 contiguously + per-row stats (mS/rS)
__device__ __forceinline__ void stage_cs(
    float* dst, const float* src, float* mO, float* rO, float* scr, int tid)
{
    const int wv = tid >> 6, ln = tid & 63;
    float sum[8], sq[8];
    #pragma unroll
    for (int u = 0; u < 8; ++u) {
        float2 v = cload2(src + u * 512 + tid * 2);
        *(float2*)(dst + u * RP + tid * 2) = v;
        sum[u] = v.x + v.y; sq[u] = v.x * v.x + v.y * v.y;
    }
    #pragma unroll
    for (int u = 0; u < 8; ++u) {
        #pragma unroll
        for (int off = 32; off; off >>= 1) {
            sum[u] += __shfl_xor(sum[u], off);
            sq[u]  += __shfl_xor(sq[u], off);
        }
    }
    if (ln == 0) {
        #pragma unroll
        for (int u = 0; u < 8; ++u) {
            scr[u * 4 + wv] = sum[u]; scr[32 + u * 4 + wv] = sq[u];
        }
    }
    __syncthreads();
    if (tid < 8) {
        float s = scr[tid*4] + scr[tid*4+1] + scr[tid*4+2] + scr[tid*4+3];
        float q = scr[32+tid*4] + scr[32+tid*4+1] + scr[32+tid*4+2] + scr[32+tid*4+3];
        float m = s * (1.f / 512.f);
        mO[tid] = m; rO[tid] = rsqrtf(q * (1.f / 512.f) - m * m + 1e-5f);
    }
    __syncthreads();
}

// ------------------------------------------------------------ LDS GEMV pieces
template <int NCOL, int KTOT>
__device__ __forceinline__ void gemv_accum(
    const __half* wcol0, int ldw, int wkoff, const float* xsL, float acc[8], int tid)
{
    constexpr int NKS = 256 / NCOL;
    const int c = tid / NKS, ks = tid % NKS;
    const __half* w = wcol0 + (size_t)c * ldw + wkoff;
    #pragma unroll
    for (int j = 0; j < KTOT / (NKS * 4); ++j) {
        int k = j * (NKS * 4) + ks * 4;
        const __half2* w2 = (const __half2*)(w + k);
        float2 f0 = __half22float2(w2[0]);
        float2 f1 = __half22float2(w2[1]);
        #pragma unroll
        for (int r = 0; r < 8; ++r) {
            const float4 xv = *(const float4*)(xsL + r * RP + k);
            acc[r] += xv.x * f0.x + xv.y * f0.y + xv.z * f1.x + xv.w * f1.y;
        }
    }
}

template <int INLN, int RESLN, int RELU>
__device__ __forceinline__ void emit_one(
    int out_i, float v, int gcol0,
    const float* SGW, const float* BWp,
    const float* mS_, const float* rS_,
    const float* rsL, const float* resg, const float* resb,
    float* out, int outN)
{
    int c2 = out_i >> 3, r = out_i & 7;
    int g = gcol0 + c2;
    if (INLN) v = rS_[r] * (v - mS_[r] * SGW[g]);
    v += BWp[g];
    if (RELU) v = fmaxf(v, 0.f);
    if (RESLN) {
        float rv = rsL[r * RP + g];
        v += (rv - mS_[r]) * rS_[r] * resg[g] + resb[g];
    }
    cstore(out + (size_t)r * outN + g, v);
}

template <int NCOL, int INLN, int RESLN, int RELU>
__device__ __forceinline__ void gemv_finish(
    float acc[8], float* part, int tid, int gcol0,
    const float* SGW, const float* BWp,
    const float* mS_, const float* rS_,
    const float* rsL, const float* resg, const float* resb,
    float* out, int outN)
{
    constexpr int NKS = 256 / NCOL, PP = NKS + 1;
    const int c = tid / NKS, ks = tid % NKS;
    #pragma unroll
    for (int r = 0; r < 8; ++r) part[(c * 8 + r) * PP + ks] = acc[r];
    __syncthreads();
    if (NCOL == 2) {
        int out_i = tid >> 4, t16 = tid & 15;
        float v = 0.f;
        #pragma unroll
        for (int j = 0; j < 8; ++j) v += part[out_i * PP + t16 + 16 * j];
        for (int off = 8; off; off >>= 1) v += __shfl_down(v, off, 16);
        if (t16 == 0)
            emit_one<INLN, RESLN, RELU>(out_i, v, gcol0, SGW, BWp, mS_, rS_,
                                        rsL, resg, resb, out, outN);
    } else {
        int out_i = tid >> 2, t4 = tid & 3;
        float v = 0.f;
        #pragma unroll
        for (int j = 0; j < 8; ++j) v += part[out_i * PP + t4 + 4 * j];
        v += __shfl_down(v, 2, 4); v += __shfl_down(v, 1, 4);
        if (t4 == 0)
            emit_one<INLN, RESLN, RELU>(out_i, v, gcol0, SGW, BWp, mS_, rS_,
                                        rsL, resg, resb, out, outN);
    }
    __syncthreads();
}

// ---------------------------------------------------------------- megakernel
struct MegaParams {
    const float *emb;
    const float *sa_out_b, *ca_out_b, *ffn_b2;
    const float *ln1_g, *ln1_b, *ln2_g, *ln2_b, *ln3_g, *ln3_b;
    const __half *qkvGW16, *saout16, *caq16, *caout16, *ffn116, *ffn216, *clfGW16;
    const float *qkvSGW, *qkvBW, *caqSGW, *caqBW, *ffn1SGW, *ffn1BW, *clfSGW, *clfBW;
    const float *EQ, *PEQ, *peR;
    int *tokens, *flags, *release, *paflag, *clfflag;
    float *Kmem, *Vmem;
    float *y1acc, *y2acc, *hb, *y3;
    float *out_logits, *out_sampled;
};

__device__ __forceinline__ void cp16(__half* dst, const __half* src, int halfs, int tid) {
    const int4* s = (const int4*)src;
    int4* d = (int4*)dst;
    int n = halfs >> 3;
    for (int i = tid; i < n; i += 256) d[i] = s[i];
}

__global__ __launch_bounds__(256, 1) void mega_kernel(MegaParams p) {
    __shared__ __align__(16) __half wff[WTOT];        // 49.6 KB
    __shared__ float kvK[NLAYER * LLEN * KVP];        // 25.3 KB
    __shared__ float kvV[NLAYER * LLEN * KVP];        // 25.3 KB
    __shared__ float rs[BB * RP];                     // 16.6 KB
    __shared__ float xs[BB * RP];                     // 16.6 KB
    __shared__ float part[2112];                      // 8.4 KB
    __shared__ float scr[64];
    __shared__ float qsh[64];
    __shared__ float mS[8], rS[8];
    __shared__ int   tokS;
    __shared__ float argv[2];
    __shared__ int   argi[2];
    const int tid = threadIdx.x, bid = blockIdx.x;
    const int ab = bid >> 3, ah = bid & 7;
    int g = 0;

    for (int l = 0; l < NLAYER; ++l) {
        cp16(wff + OFF_FFN1 + l * 4160, p.ffn116 + ((size_t)l * 2048 + bid * 8) * WLD, 8 * WLD, tid);
        cp16(wff + OFF_FFN2 + l * 4112, p.ffn216 + ((size_t)l * 512 + bid * 2) * WLD2, 2 * WLD2, tid);
    }
    __syncthreads();

    for (int t = 0; t < LLEN; ++t) {
        for (int l = 0; l < NLAYER; ++l) {
            // ======== PA: [clf+embed | qkv-fold] + self-attn + saout-fold ========
            if (bid < 64) {
                const int b = ab, h = ah;
                if (l == 0) {
                    if (t > 0) {
                        // in-block classifier for step t-1 (redundant per head, bit-identical)
                        stage_row(rs, p.y3 + b * DD, scr, tid, 1);
                        {
                            int cl = tid & 127, kh = tid >> 7;
                            const __half2* w2 = (const __half2*)(p.clfGW16 + (size_t)cl * 512 + kh * 256);
                            const float* xh = rs + kh * 256;
                            float lg = 0.f;
                            #pragma unroll 8
                            for (int k2 = 0; k2 < 128; ++k2) {
                                float2 fw = __half22float2(w2[k2]);
                                lg += xh[2 * k2] * fw.x + xh[2 * k2 + 1] * fw.y;
                            }
                            part[tid] = lg;
                        }
                        __syncthreads();
                        if (tid < 128) {
                            float m = scr[8], ri = scr[9];
                            float lg = ri * ((part[tid] + part[128 + tid]) - m * p.clfSGW[tid]) + p.clfBW[tid];
                            if (h == 0) p.out_logits[((size_t)b * LLEN + (t - 1)) * VV + tid] = lg;
                            float bv = lg; int bi = tid;
                            for (int off = 32; off; off >>= 1) {
                                float ov = __shfl_xor(bv, off); int oi = __shfl_xor(bi, off);
                                if (ov > bv || (ov == bv && oi < bi)) { bv = ov; bi = oi; }
                            }
                            if ((tid & 63) == 0) { argv[tid >> 6] = bv; argi[tid >> 6] = bi; }
                        }
                        __syncthreads();
                        if (tid == 0) {
                            int best = (argv[1] > argv[0] || (argv[1] == argv[0] && argi[1] < argi[0]))
                                           ? argi[1] : argi[0];
                            tokS = best;
                            if (h == 0) icstore(p.tokens + b * (LLEN + 1) + t, best);
                        }
                        __syncthreads();
                    } else {
                        if (tid == 0) tokS = icload(p.tokens + b * (LLEN + 1));  // SOS
                        __syncthreads();
                    }
                    const int tok = tokS;
                    // residual rs = emb*scale + pe; q/k/v head slices from EQ+PEQ
                    {
                        const float* er = p.emb + (size_t)tok * DD;
                        const float* pr = p.peR + (size_t)t * DD;
                        rs[tid * 2]     = er[tid * 2] * EMB_SCALE + pr[tid * 2];
                        rs[tid * 2 + 1] = er[tid * 2 + 1] * EMB_SCALE + pr[tid * 2 + 1];
                    }
                    {
                        const float* eq = p.EQ + (size_t)tok * (3 * DD);
                        const float* pq = p.PEQ + (size_t)t * (3 * DD);
                        if (tid < 64) qsh[tid] = eq[h * HDIM + tid] + pq[h * HDIM + tid];
                        else if (tid < 128) {
                            int c = tid - 64;
                            kvK[t * KVP + c] = eq[DD + h * HDIM + c] + pq[DD + h * HDIM + c];
                        } else if (tid < 192) {
                            int c = tid - 128;
                            kvV[t * KVP + c] = eq[2 * DD + h * HDIM + c] + pq[2 * DD + h * HDIM + c];
                        }
                    }
                    __syncthreads();
                } else {
                    stage_row(rs, p.y3 + b * DD, scr, tid, 1);     // LN3 stats
                    const float m0 = scr[8], r0 = scr[9];
                    const int c = tid & 63, ks = tid >> 6;
                    #pragma unroll
                    for (int m = 0; m < 3; ++m) {
                        const __half2* w2 = (const __half2*)(p.qkvGW16 +
                            ((size_t)((l - 1) * 1536 + m * 512 + h * HDIM + c)) * WLD + ks * 128);
                        const float* x0 = rs + ks * 128;
                        float a = 0.f;
                        #pragma unroll 16
                        for (int i2 = 0; i2 < 64; ++i2) {
                            float2 fw = __half22float2(w2[i2]);
                            a += x0[2 * i2] * fw.x + x0[2 * i2 + 1] * fw.y;
                        }
                        part[m * 256 + ks * 64 + c] = a;
                    }
                    __syncthreads();
                    if (tid < 192) {
                        int m = tid >> 6, c2 = tid & 63;
                        float raw = part[m * 256 + c2] + part[m * 256 + 64 + c2]
                                  + part[m * 256 + 128 + c2] + part[m * 256 + 192 + c2];
                        int gc = (l - 1) * 1536 + m * 512 + h * HDIM + c2;
                        float val = r0 * (raw - m0 * p.qkvSGW[gc]) + p.qkvBW[gc];
                        if (m == 0)      qsh[c2] = val;
                        else if (m == 1) kvK[(l * LLEN + t) * KVP + c2] = val;
                        else             kvV[(l * LLEN + t) * KVP + c2] = val;
                    }
                    __syncthreads();
                }
                // ---- self-attn over LDS KV ----
                if (tid <= t) {
                    const float* kr = kvK + (l * LLEN + tid) * KVP;
                    float s = 0.f;
                    #pragma unroll 16
                    for (int d = 0; d < HDIM; ++d) s += qsh[d] * kr[d];
                    part[tid] = s * 0.125f;
                }
                __syncthreads();
                if (tid < 64) {
                    float s = (tid <= t) ? part[tid] : -1e30f;
                    float mx = s;
                    for (int off = 32; off; off >>= 1) mx = fmaxf(mx, __shfl_xor(mx, off));
                    float pe = (tid <= t) ? expf(s - mx) : 0.f;
                    float sum = pe;
                    for (int off = 32; off; off >>= 1) sum += __shfl_xor(sum, off);
                    if (tid <= t) part[tid] = pe / sum;
                }
                __syncthreads();
                if (tid < 64) {
                    float o = 0.f;
                    for (int j = 0; j <= t; ++j) o += part[j] * kvV[(l * LLEN + j) * KVP + tid];
                    part[64 + tid] = o;
                }
                __syncthreads();
                // ---- saout-fold -> atomic y1acc ----
                {
                    const int c0 = tid * 2;
                    const float m0 = scr[8], r0 = scr[9];
                    const __half* w0 = p.saout16 + ((size_t)(l * 512 + c0)) * WLD + h * HDIM;
                    const __half* w1 = w0 + WLD;
                    float a0 = 0.f, a1 = 0.f;
                    #pragma unroll 16
                    for (int d = 0; d < HDIM; ++d) {
                        float pv = part[64 + d];
                        a0 += pv * __half2float(w0[d]);
                        a1 += pv * __half2float(w1[d]);
                    }
                    if (h == 0) {
                        float x0r = rs[c0], x1r = rs[c0 + 1];
                        if (l > 0) {
                            x0r = (x0r - m0) * r0 * p.ln3_g[(l - 1) * DD + c0] + p.ln3_b[(l - 1) * DD + c0];
                            x1r = (x1r - m0) * r0 * p.ln3_g[(l - 1) * DD + c0 + 1] + p.ln3_b[(l - 1) * DD + c0 + 1];
                        }
                        a0 += p.sa_out_b[l * DD + c0] + x0r;
                        a1 += p.sa_out_b[l * DD + c0 + 1] + x1r;
                    }
                    atomicAdd(p.y1acc + b * DD + c0, a0);
                    atomicAdd(p.y1acc + b * DD + c0 + 1, a1);
                }
                // zero this head's y2acc slice for PB accumulation
                if (tid < 64) cstore(p.y2acc + b * DD + h * HDIM + tid, 0.f);
                // ---- row-local arrive ----
                asm volatile("s_waitcnt vmcnt(0)" ::: "memory");
                __syncthreads();
                if (tid == 0) icstore(p.paflag + b * 16 + h, t * NLAYER + l + 1);

                // ======== PB: wait row, caq-fold + cross-attn + caout-fold ========
                if (tid < 8) {
                    int spins = 0;
                    while (icload(p.paflag + b * 16 + tid) < t * NLAYER + l + 1) {
                        __builtin_amdgcn_s_sleep(2);
                        if (++spins > (1 << 17)) break;
                    }
                }
                __syncthreads();
                stage_row(rs, p.y1acc + b * DD, scr, tid, 1);      // LN1 stats
                const float m0 = scr[8], r0 = scr[9];
                {
                    const int c = tid & 63, ks = tid >> 6;
                    const __half2* w2 = (const __half2*)(p.caq16 +
                        ((size_t)(l * 512 + h * HDIM + c)) * WLD + ks * 128);
                    const float* x0 = rs + ks * 128;
                    float a = 0.f;
                    #pragma unroll 16
                    for (int i2 = 0; i2 < 64; ++i2) {
                        float2 fw = __half22float2(w2[i2]);
                        a += x0[2 * i2] * fw.x + x0[2 * i2 + 1] * fw.y;
                    }
                    part[ks * 64 + c] = a;
                }
                __syncthreads();
                if (tid < 64) {
                    float raw = part[tid] + part[64 + tid] + part[128 + tid] + part[192 + tid];
                    int gc = l * 512 + h * HDIM + tid;
                    qsh[tid] = r0 * (raw - m0 * p.caqSGW[gc]) + p.caqBW[gc];
                }
                __syncthreads();
                float* sc = part + 256;
                if (tid < 128) {
                    const float* kp = p.Kmem + (((size_t)(l * 8 + b)) * SMEMN + tid) * DD + h * HDIM;
                    float s = 0.f;
                    #pragma unroll 8
                    for (int d = 0; d < HDIM; ++d) s += qsh[d] * kp[d];
                    sc[tid] = s * 0.125f;
                }
                __syncthreads();
                if (tid < 64) {
                    float s0 = sc[tid], s1 = sc[tid + 64];
                    float mx = fmaxf(s0, s1);
                    for (int off = 32; off; off >>= 1) mx = fmaxf(mx, __shfl_xor(mx, off));
                    float e0 = expf(s0 - mx), e1 = expf(s1 - mx);
                    float sum = e0 + e1;
                    for (int off = 32; off; off >>= 1) sum += __shfl_xor(sum, off);
                    sc[tid] = e0 / sum; sc[tid + 64] = e1 / sum;
                }
                __syncthreads();
                float* po = part + 384;
                if (tid < 128) {
                    int d = tid & 63, half = tid >> 6;
                    const float* Vb = p.Vmem + (((size_t)(l * 8 + b)) * SMEMN + half * 64) * DD + h * HDIM + d;
                    float o = 0.f;
                    for (int j = 0; j < 64; ++j) o += sc[half * 64 + j] * Vb[(size_t)j * DD];
                    po[half * 64 + d] = o;
                }
                __syncthreads();
                if (tid < 64) part[512 + tid] = po[tid] + po[64 + tid];
                __syncthreads();
                {
                    const int c0 = tid * 2;
                    const __half* w0 = p.caout16 + ((size_t)(l * 512 + c0)) * WLD + h * HDIM;
                    const __half* w1 = w0 + WLD;
                    float a0 = 0.f, a1 = 0.f;
                    #pragma unroll 16
                    for (int d = 0; d < HDIM; ++d) {
                        float cv = part[512 + d];
                        a0 += cv * __half2float(w0[d]);
                        a1 += cv * __half2float(w1[d]);
                    }
                    if (h == 0) {
                        float r0v = (rs[c0] - m0) * r0 * p.ln1_g[l * DD + c0] + p.ln1_b[l * DD + c0];
                        float r1v = (rs[c0 + 1] - m0) * r0 * p.ln1_g[l * DD + c0 + 1] + p.ln1_b[l * DD + c0 + 1];
                        a0 += p.ca_out_b[l * DD + c0] + r0v;
                        a1 += p.ca_out_b[l * DD + c0 + 1] + r1v;
                    }
                    atomicAdd(p.y2acc + b * DD + c0, a0);
                    atomicAdd(p.y2acc + b * DD + c0 + 1, a1);
                }
            }
            ++g; gbar(p.flags, p.release, g, bid, tid);   // PB-end (global)

            // ======== PC: ffn1 (LN2-folded, relu) ========
            {
                stage_cs(rs, p.y2acc, mS, rS, scr, tid);
                float acc[8] = {};
                gemv_accum<8, 512>(wff + OFF_FFN1 + l * 4160, WLD, 0, rs, acc, tid);
                gemv_finish<8, 1, 0, 1>(acc, part, tid, bid * 8,
                    p.ffn1SGW + l * DFFN, p.ffn1BW + l * DFFN, mS, rS,
                    nullptr, nullptr, nullptr, p.hb, DFFN);
                if (bid >= 240)
                    cstore(p.y1acc + (bid - 240) * 256 + tid, 0.f);
            }
            ++g; gbar(p.flags, p.release, g, bid, tid);

            // ======== PD: ffn2 (K=2048, 4 chunks) + LN2 residual ========
            {
                float acc[8] = {};
                #pragma unroll
                for (int ch = 0; ch < 4; ++ch) {
                    #pragma unroll
                    for (int u = 0; u < 8; ++u) {
                        float2 v = cload2(p.hb + u * DFFN + ch * 512 + tid * 2);
                        *(float2*)(xs + u * RP + tid * 2) = v;
                    }
                    __syncthreads();
                    gemv_accum<2, 512>(wff + OFF_FFN2 + l * 4112, WLD2, ch * 512, xs, acc, tid);
                    __syncthreads();
                }
                gemv_finish<2, 0, 1, 0>(acc, part, tid, bid * 2,
                    nullptr, p.ffn_b2 + l * DD, mS, rS,
                    rs, p.ln2_g + l * DD, p.ln2_b + l * DD, p.y3, DD);
            }
            ++g; gbar(p.flags, p.release, g, bid, tid);
        }
        // (no CLF phase — folded into next step's PA)
    }

    // ---- epilogue: logits/tokens for final step (blocks 0-7) ----
    if (bid < 8) {
        const int b = bid;
        stage_row(rs, p.y3 + b * DD, scr, tid, 1);
        {
            int cl = tid & 127, kh = tid >> 7;
            const __half2* w2 = (const __half2*)(p.clfGW16 + (size_t)cl * 512 + kh * 256);
            const float* xh = rs + kh * 256;
            float lg = 0.f;
            #pragma unroll 8
            for (int k2 = 0; k2 < 128; ++k2) {
                float2 fw = __half22float2(w2[k2]);
                lg += xh[2 * k2] * fw.x + xh[2 * k2 + 1] * fw.y;
            }
            part[tid] = lg;
        }
        __syncthreads();
        if (tid < 128) {
            float m = scr[8], ri = scr[9];
            float lg = ri * ((part[tid] + part[128 + tid]) - m * p.clfSGW[tid]) + p.clfBW[tid];
            p.out_logits[((size_t)b * LLEN + (LLEN - 1)) * VV + tid] = lg;
            float bv = lg; int bi = tid;
            for (int off = 32; off; off >>= 1) {
                float ov = __shfl_xor(bv, off); int oi = __shfl_xor(bi, off);
                if (ov > bv || (ov == bv && oi < bi)) { bv = ov; bi = oi; }
            }
            if ((tid & 63) == 0) { argv[tid >> 6] = bv; argi[tid >> 6] = bi; }
        }
        __syncthreads();
        if (tid == 0) {
            int best = (argv[1] > argv[0] || (argv[1] == argv[0] && argi[1] < argi[0]))
                           ? argi[1] : argi[0];
            icstore(p.tokens + b * (LLEN + 1) + LLEN, best);
        }
        asm volatile("s_waitcnt vmcnt(0)" ::: "memory");
        __syncthreads();
        if (tid == 0) icstore(p.clfflag + b * 16, 1);
    }

    // ---- finalize sampled (block 0) ----
    if (bid == 0) {
        if (tid < 8) {
            int spins = 0;
            while (icload(p.clfflag + tid * 16) < 1) {
                __builtin_amdgcn_s_sleep(2);
                if (++spins > (1 << 17)) break;
            }
        }
        __syncthreads();
        if (tid < BB) {
            int b = tid;
            int toks[LLEN + 1];
            for (int j = 0; j <= LLEN; j++) toks[j] = icload(p.tokens + b * (LLEN + 1) + j);
            int eos = 0;
            for (int j = 1; j <= LLEN; j++)
                if (toks[j] == EOS_T) { eos = j; break; }
            for (int j = 0; j <= LLEN; j++) {
                int v = toks[j];
                if (eos != 0 && j > eos + 1) v = PAD_T;
                p.out_sampled[b * (LLEN + 1) + j] = (float)v;
            }
        }
    }
}

// --------------------------------------------------------------------- host
extern "C" void kernel_launch(void* const* d_in, const int* in_sizes, int n_in,
                              void* d_out, int out_size, void* d_ws, size_t ws_size,
                              hipStream_t stream) {
    const float* memory   = (const float*)d_in[0];
    const float* emb      = (const float*)d_in[1];
    const float* sa_qkv_w = (const float*)d_in[2];
    const float* sa_qkv_b = (const float*)d_in[3];
    const float* sa_out_w = (const float*)d_in[4];
    const float* sa_out_b = (const float*)d_in[5];
    const float* ca_q_w   = (const float*)d_in[6];
    const float* ca_q_b   = (const float*)d_in[7];
    const float* ca_kv_w  = (const float*)d_in[8];
    const float* ca_kv_b  = (const float*)d_in[9];
    const float* ca_out_w = (const float*)d_in[10];
    const float* ca_out_b = (const float*)d_in[11];
    const float* ln1_g    = (const float*)d_in[12];
    const float* ln1_b    = (const float*)d_in[13];
    const float* ln2_g    = (const float*)d_in[14];
    const float* ln2_b    = (const float*)d_in[15];
    const float* ln3_g    = (const float*)d_in[16];
    const float* ln3_b    = (const float*)d_in[17];
    const float* ffn_w1   = (const float*)d_in[18];
    const float* ffn_b1   = (const float*)d_in[19];
    const float* ffn_w2   = (const float*)d_in[20];
    const float* ffn_b2   = (const float*)d_in[21];
    const float* clf_w    = (const float*)d_in[22];
    const float* clf_b    = (const float*)d_in[23];

    float* f   = (float*)d_ws;
    int*   wsI = (int*)d_ws;
    int* flags   = wsI;            // 4096 ints
    int* release = wsI + 4096;     // 128
    int* paflag  = wsI + 4224;     // 128
    int* clfflag = wsI + 4352;     // 128
    int* tokens  = wsI + 4480;     // 264 -> ends at int 4744
    float* y1acc = f + 4864;       // 4096
    float* y2acc = y1acc + 4096;   // 4096 -> 13056
    float* peR   = f + 13056;      // 16384
    float* Kmem  = peR + (size_t)LLEN * DD;
    float* Vmem  = Kmem + (size_t)NLAYER * BB * SMEMN * DD;
    float* hb    = Vmem + (size_t)NLAYER * BB * SMEMN * DD;
    float* y3    = hb + BB * DFFN;
    float* EQ    = y3 + BB * DD;
    float* PEQ   = EQ + (size_t)VV * 3 * DD;
    float* qkvSGW = PEQ + (size_t)LLEN * 3 * DD;
    float* qkvBW  = qkvSGW + 2 * 1536;
    float* caqSGW = qkvBW + 2 * 1536;
    float* caqBW  = caqSGW + 3 * 512;
    float* ffn1SGW = caqBW + 3 * 512;
    float* ffn1BW  = ffn1SGW + 3 * 2048;
    float* clfSGW  = ffn1BW + 3 * 2048;
    float* clfBW   = clfSGW + 128;
    __half* qkvGW16 = (__half*)(clfBW + 128);
    __half* saout16 = qkvGW16 + (size_t)2 * 1536 * WLD;
    __half* caq16   = saout16 + (size_t)3 * 512 * WLD;
    __half* caout16 = caq16   + (size_t)3 * 512 * WLD;
    __half* ffn116  = caout16 + (size_t)3 * 512 * WLD;
    __half* ffn216  = ffn116  + (size_t)3 * 2048 * WLD;
    __half* clfGW16 = ffn216  + (size_t)3 * 512 * WLD2;

    float* out_logits  = (float*)d_out;
    float* out_sampled = out_logits + (size_t)BB * LLEN * VV;

    hipMemsetAsync(d_ws, 0, 52224, stream);  // flags/release/paflag/clfflag/tokens/y1acc/y2acc

    ProParams q;
    q.memory = memory; q.emb = emb;
    q.sa_qkv_w = sa_qkv_w; q.sa_qkv_b = sa_qkv_b; q.sa_out_w = sa_out_w;
    q.ca_q_w = ca_q_w; q.ca_q_b = ca_q_b; q.ca_kv_w = ca_kv_w; q.ca_kv_b = ca_kv_b;
    q.ca_out_w = ca_out_w;
    q.ln1_g = ln1_g; q.ln1_b = ln1_b; q.ln2_g = ln2_g; q.ln2_b = ln2_b;
    q.ln3_g = ln3_g; q.ln3_b = ln3_b;
    q.ffn_w1 = ffn_w1; q.ffn_b1 = ffn_b1; q.ffn_w2 = ffn_w2;
    q.clf_w = clf_w; q.clf_b = clf_b;
    q.tokens = tokens; q.peR = peR; q.Kmem = Kmem; q.Vmem = Vmem;
    q.EQ = EQ; q.PEQ = PEQ;
    q.qkvSGW = qkvSGW; q.qkvBW = qkvBW; q.caqSGW = caqSGW; q.caqBW = caqBW;
    q.ffn1SGW = ffn1SGW; q.ffn1BW = ffn1BW; q.clfSGW = clfSGW; q.clfBW = clfBW;
    q.qkvGW16 = qkvGW16; q.saout16 = saout16; q.caq16 = caq16; q.caout16 = caout16;
    q.ffn116 = ffn116; q.ffn216 = ffn216; q.clfGW16 = clfGW16;
    k_prologue<<<11020, 256, 0, stream>>>(q);

    MegaParams p;
    p.emb = emb;
    p.sa_out_b = sa_out_b; p.ca_out_b = ca_out_b; p.ffn_b2 = ffn_b2;
    p.ln1_g = ln1_g; p.ln1_b = ln1_b;
    p.ln2_g = ln2_g; p.ln2_b = ln2_b;
    p.ln3_g = ln3_g; p.ln3_b = ln3_b;
    p.qkvGW16 = qkvGW16; p.saout16 = saout16; p.caq16 = caq16; p.caout16 = caout16;
    p.ffn116 = ffn116; p.ffn216 = ffn216; p.clfGW16 = clfGW16;
    p.qkvSGW = qkvSGW; p.qkvBW = qkvBW; p.caqSGW = caqSGW; p.caqBW = caqBW;
    p.ffn1SGW = ffn1SGW; p.ffn1BW = ffn1BW; p.clfSGW = clfSGW; p.clfBW = clfBW;
    p.EQ = EQ; p.PEQ = PEQ; p.peR = peR;
    p.tokens = tokens; p.flags = flags; p.release = release;
    p.paflag = paflag; p.clfflag = clfflag;
    p.Kmem = Kmem; p.Vmem = Vmem;
    p.y1acc = y1acc; p.y2acc = y2acc; p.hb = hb; p.y3 = y3;
    p.out_logits = out_logits; p.out_sampled = out_sampled;

    mega_kernel<<<NB, 256, 0, stream>>>(p);
}

// Round 10
// 3394.131 us; speedup vs baseline: 2.3551x; 1.5248x over previous
//
#include <hip/hip_runtime.h>
#include <hip/hip_fp16.h>
#include <math.h>

#define BB 8
#define SMEMN 128
#define DD 512
#define HDIM 64
#define DFFN 2048
#define NLAYER 3
#define VV 128
#define LLEN 32
#define SOS_T 1
#define EOS_T 2
#define PAD_T 0
#define NB 256
#define WLD 520          // weight col pitch (halfs), K=512 mats
#define WLD2 2056        // ffn2 col pitch (halfs), K=2048
#define KVP 66           // LDS KV row pitch (floats)
#define EMB_SCALE 22.62741699796952f

// ---- agent-scope (sc1) accessors
__device__ __forceinline__ float cload(const float* p) {
    return __hip_atomic_load(p, __ATOMIC_RELAXED, __HIP_MEMORY_SCOPE_AGENT);
}
__device__ __forceinline__ float2 cload2(const float* p) {
    unsigned long long u = __hip_atomic_load((const unsigned long long*)p,
                                             __ATOMIC_RELAXED, __HIP_MEMORY_SCOPE_AGENT);
    union { unsigned long long u; float2 f; } c; c.u = u; return c.f;
}
__device__ __forceinline__ void cstore(float* p, float v) {
    __hip_atomic_store(p, v, __ATOMIC_RELAXED, __HIP_MEMORY_SCOPE_AGENT);
}
__device__ __forceinline__ int icload(const int* p) {
    return __hip_atomic_load(p, __ATOMIC_RELAXED, __HIP_MEMORY_SCOPE_AGENT);
}
__device__ __forceinline__ void icstore(int* p, int v) {
    __hip_atomic_store(p, v, __ATOMIC_RELAXED, __HIP_MEMORY_SCOPE_AGENT);
}

// ================================================================ prologue
struct ProParams {
    const float *memory, *emb;
    const float *sa_qkv_w, *sa_qkv_b, *sa_out_w;
    const float *ca_q_w, *ca_q_b, *ca_kv_w, *ca_kv_b, *ca_out_w;
    const float *ln1_g, *ln1_b, *ln2_g, *ln2_b, *ln3_g, *ln3_b;
    const float *ffn_w1, *ffn_b1, *ffn_w2, *clf_w, *clf_b;
    int* tokens;
    float *peR, *Kmem, *Vmem, *EQ, *PEQ;
    float *qkvSGW, *qkvBW, *caqSGW, *caqBW, *ffn1SGW, *ffn1BW, *clfSGW, *clfBW;
    __half *qkvGW16, *saout16, *caq16, *caout16, *ffn116, *ffn216, *clfGW16;
};

__device__ void dev_t16pad(int bl, const float* src, const float* g, __half* dst,
                           int K, int N, int KPAD, float* tile, int tid) {
    int nbx = K >> 5, nby = N >> 5;
    int bx = bl % nbx; int rest = bl / nbx;
    int by = rest % nby; int z = rest / nby;
    int k0 = bx * 32, n0 = by * 32;
    const float* s = src + (size_t)z * K * N;
    __half* d = dst + (size_t)z * N * KPAD;
    int r = tid >> 5, c = tid & 31;
    #pragma unroll
    for (int i = 0; i < 4; i++) {
        int kk = k0 + r + i * 8;
        float gv = g ? g[(size_t)z * K + kk] : 1.f;
        tile[(r + i * 8) * 33 + c] = s[(size_t)kk * N + n0 + c] * gv;
    }
    __syncthreads();
    #pragma unroll
    for (int i = 0; i < 4; i++)
        d[(size_t)(n0 + r + i * 8) * KPAD + k0 + c] = (__half)tile[c * 33 + r + i * 8];
}

__device__ void dev_colvec(int bl, int nx, const float* W, const float* g, const float* b,
                           const float* bias, float* SGW, float* BW, int K, int N, int tid) {
    int bx = bl % nx, z = bl / nx;
    int c = bx * 256 + tid;
    if (c >= N) return;
    const float* Wz = W + (size_t)z * K * N;
    float sg = 0.f, bw = 0.f;
    for (int k = 0; k < K; ++k) {
        float w = Wz[(size_t)k * N + c];
        sg += g[(size_t)z * K + k] * w;
        bw += b[(size_t)z * K + k] * w;
    }
    SGW[(size_t)z * N + c] = sg;
    BW[(size_t)z * N + c] = bw + bias[(size_t)z * N + c];
}

__device__ void dev_eqpeq(int row, const float* emb, const float* W0, const float* b0,
                          float* EQ, float* PEQ, float* x, int tid) {
    bool isE = row < VV;
    for (int k = tid; k < DD; k += 256) {
        if (isE) x[k] = emb[(size_t)row * DD + k] * EMB_SCALE;
        else {
            int tt = row - VV;
            int pos = (tt == 0) ? 0 : (tt + 1);
            float freq = expf((float)(k & ~1) * (-9.210340371976184f / 512.f));
            float ang = (float)pos * freq;
            x[k] = (k & 1) ? cosf(ang) : sinf(ang);
        }
    }
    __syncthreads();
    for (int c = tid; c < 3 * DD; c += 256) {
        float a = isE ? b0[c] : 0.f;
        for (int k = 0; k < DD; ++k) a += x[k] * W0[(size_t)k * (3 * DD) + c];
        if (isE) EQ[(size_t)row * (3 * DD) + c] = a;
        else     PEQ[(size_t)(row - VV) * (3 * DD) + c] = a;
    }
}

__device__ void dev_memkv(int bl, const float* mem, const float* Wkv, const float* bkv,
                          float* Kmem, float* Vmem, float* smem, int tid) {
    float* As = smem;          // [64][20]
    float* Bs = smem + 1280;   // [16][68]
    int bx = bl & 15, by = (bl >> 4) & 15, l = bl >> 8;
    const float* Wl = Wkv + (size_t)l * DD * (2 * DD);
    const float* bl_ = bkv + l * (2 * DD);
    int brow = by * 64, bcol = bx * 64;
    int ty = tid / 16, tx = tid % 16;
    float acc[4][4] = {};
    for (int k0 = 0; k0 < DD; k0 += 16) {
        {
            int r = tid >> 2, kk = (tid & 3) * 4;
            const float4 av = *(const float4*)(mem + (size_t)(brow + r) * DD + k0 + kk);
            As[r * 20 + kk] = av.x; As[r * 20 + kk + 1] = av.y;
            As[r * 20 + kk + 2] = av.z; As[r * 20 + kk + 3] = av.w;
        }
        {
            int kb = tid >> 4, jj = (tid & 15) * 4;
            const float4 bv = *(const float4*)(Wl + (size_t)(k0 + kb) * (2 * DD) + bcol + jj);
            Bs[kb * 68 + jj] = bv.x; Bs[kb * 68 + jj + 1] = bv.y;
            Bs[kb * 68 + jj + 2] = bv.z; Bs[kb * 68 + jj + 3] = bv.w;
        }
        __syncthreads();
        #pragma unroll
        for (int kk2 = 0; kk2 < 16; kk2++) {
            float a0 = As[(ty * 4 + 0) * 20 + kk2], a1 = As[(ty * 4 + 1) * 20 + kk2];
            float a2 = As[(ty * 4 + 2) * 20 + kk2], a3 = As[(ty * 4 + 3) * 20 + kk2];
            float b0 = Bs[kk2 * 68 + tx * 4 + 0], b1 = Bs[kk2 * 68 + tx * 4 + 1];
            float b2 = Bs[kk2 * 68 + tx * 4 + 2], b3 = Bs[kk2 * 68 + tx * 4 + 3];
            acc[0][0] += a0 * b0; acc[0][1] += a0 * b1; acc[0][2] += a0 * b2; acc[0][3] += a0 * b3;
            acc[1][0] += a1 * b0; acc[1][1] += a1 * b1; acc[1][2] += a1 * b2; acc[1][3] += a1 * b3;
            acc[2][0] += a2 * b0; acc[2][1] += a2 * b1; acc[2][2] += a2 * b2; acc[2][3] += a2 * b3;
            acc[3][0] += a3 * b0; acc[3][1] += a3 * b1; acc[3][2] += a3 * b2; acc[3][3] += a3 * b3;
        }
        __syncthreads();
    }
    for (int i = 0; i < 4; i++)
        for (int jj = 0; jj < 4; jj++) {
            int row = brow + ty * 4 + i, colg = bcol + tx * 4 + jj;
            float v = acc[i][jj] + bl_[colg];
            if (colg < DD) Kmem[((size_t)l * (BB * SMEMN) + row) * DD + colg] = v;
            else           Vmem[((size_t)l * (BB * SMEMN) + row) * DD + (colg - DD)] = v;
        }
}

__device__ void dev_init(int* tokens, float* peR, int tid) {
    for (int i = tid; i < BB * (LLEN + 1); i += 256)
        tokens[i] = (i % (LLEN + 1) == 0) ? SOS_T : PAD_T;
    for (int idx = tid; idx < LLEN * DD; idx += 256) {
        int t = idx >> 9, d = idx & 511;
        int pos = (t == 0) ? 0 : (t + 1);
        float freq = expf((float)(d & ~1) * (-9.210340371976184f / 512.f));
        float ang = (float)pos * freq;
        peR[idx] = (d & 1) ? cosf(ang) : sinf(ang);
    }
}

__global__ __launch_bounds__(256) void k_prologue(ProParams q) {
    __shared__ float smem[2432];
    const int tid = threadIdx.x;
    int bl = blockIdx.x;
    if (bl < 1536) {
        dev_t16pad(bl, q.sa_qkv_w + (size_t)512 * 1536, q.ln3_g, q.qkvGW16, 512, 1536, WLD, smem, tid);
    } else if ((bl -= 1536) < 768) {
        dev_t16pad(bl, q.sa_out_w, nullptr, q.saout16, 512, 512, WLD, smem, tid);
    } else if ((bl -= 768) < 768) {
        dev_t16pad(bl, q.ca_q_w, q.ln1_g, q.caq16, 512, 512, WLD, smem, tid);
    } else if ((bl -= 768) < 768) {
        dev_t16pad(bl, q.ca_out_w, nullptr, q.caout16, 512, 512, WLD, smem, tid);
    } else if ((bl -= 768) < 3072) {
        dev_t16pad(bl, q.ffn_w1, q.ln2_g, q.ffn116, 512, 2048, WLD, smem, tid);
    } else if ((bl -= 3072) < 3072) {
        dev_t16pad(bl, q.ffn_w2, nullptr, q.ffn216, 2048, 512, WLD2, smem, tid);
    } else if ((bl -= 3072) < 64) {
        dev_t16pad(bl, q.clf_w, q.ln3_g + 2 * 512, q.clfGW16, 512, 128, 512, smem, tid);
    } else if ((bl -= 64) < 12) {
        dev_colvec(bl, 6, q.sa_qkv_w + (size_t)512 * 1536, q.ln3_g, q.ln3_b,
                   q.sa_qkv_b + 1536, q.qkvSGW, q.qkvBW, 512, 1536, tid);
    } else if ((bl -= 12) < 6) {
        dev_colvec(bl, 2, q.ca_q_w, q.ln1_g, q.ln1_b, q.ca_q_b, q.caqSGW, q.caqBW, 512, 512, tid);
    } else if ((bl -= 6) < 24) {
        dev_colvec(bl, 8, q.ffn_w1, q.ln2_g, q.ln2_b, q.ffn_b1, q.ffn1SGW, q.ffn1BW, 512, 2048, tid);
    } else if ((bl -= 24) < 1) {
        dev_colvec(0, 1, q.clf_w, q.ln3_g + 1024, q.ln3_b + 1024, q.clf_b,
                   q.clfSGW, q.clfBW, 512, 128, tid);
    } else if ((bl -= 1) < 160) {
        dev_eqpeq(bl, q.emb, q.sa_qkv_w, q.sa_qkv_b, q.EQ, q.PEQ, smem, tid);
    } else if ((bl -= 160) < 768) {
        dev_memkv(bl, q.memory, q.ca_kv_w, q.ca_kv_b, q.Kmem, q.Vmem, smem, tid);
    } else {
        dev_init(q.tokens, q.peR, tid);
    }
}

// ----------------------------- row-local sync
__device__ __forceinline__ void rarrive(int* rf, int j, int gen) {
    asm volatile("s_waitcnt vmcnt(0)" ::: "memory");
    __syncthreads();
    if (threadIdx.x == 0) icstore(rf + j, gen);
}
__device__ __forceinline__ void rwait(const int* rf, int n, int gen, int tid) {
    if (tid < n) {
        int spins = 0;
        while (icload(rf + tid) < gen) {
            if (spins > 16) __builtin_amdgcn_s_sleep(2);
            if (++spins > (1 << 17)) break;   // escape hatch
        }
    }
    __syncthreads();
}

// -------------- stage one 512-row + optional stats (m -> scr[8], r -> scr[9])
__device__ __forceinline__ void stage_row(
    float* dst, const float* src, float* scr, int tid, int dostats)
{
    float2 v = cload2(src + tid * 2);
    dst[tid * 2] = v.x; dst[tid * 2 + 1] = v.y;
    if (dostats) {
        float sum = v.x + v.y, sq = v.x * v.x + v.y * v.y;
        #pragma unroll
        for (int off = 32; off; off >>= 1) {
            sum += __shfl_xor(sum, off); sq += __shfl_xor(sq, off);
        }
        if ((tid & 63) == 0) { scr[tid >> 6] = sum; scr[4 + (tid >> 6)] = sq; }
        __syncthreads();
        if (tid == 0) {
            float s = scr[0] + scr[1] + scr[2] + scr[3];
            float q = scr[4] + scr[5] + scr[6] + scr[7];
            float m = s * (1.f / 512.f);
            scr[8] = m; scr[9] = rsqrtf(q * (1.f / 512.f) - m * m + 1e-5f);
        }
    }
    __syncthreads();
}

// ---------------------------------------------------------------- megakernel
struct MegaParams {
    const float *emb;
    const float *sa_out_b, *ca_out_b, *ffn_b2;
    const float *ln1_g, *ln1_b, *ln2_g, *ln2_b, *ln3_g, *ln3_b;
    const __half *qkvGW16, *saout16, *caq16, *caout16, *ffn116, *ffn216, *clfGW16;
    const float *qkvSGW, *qkvBW, *caqSGW, *caqBW, *ffn1SGW, *ffn1BW, *clfSGW, *clfBW;
    const float *EQ, *PEQ, *peR;
    int *tokens, *rflags, *clfflag;
    float *Kmem, *Vmem;
    float *y1acc, *y2acc, *hb, *y3;
    float *out_logits, *out_sampled;
};

__global__ __launch_bounds__(256, 1) void mega_kernel(MegaParams p) {
    __shared__ float kvK[NLAYER * LLEN * KVP];        // 25.3 KB (head blocks only)
    __shared__ float kvV[NLAYER * LLEN * KVP];        // 25.3 KB
    __shared__ float rs[DD];                          // 2 KB row staging
    __shared__ float xs[16 * 130];                    // 8.1 KB hb staging (pitched)
    __shared__ float part[1024];                      // 4 KB scratch
    __shared__ float scr[16];
    __shared__ float qsh[64];
    __shared__ int   tokS;
    __shared__ float argv[2];
    __shared__ int   argi[2];
    const int tid = threadIdx.x, bid = blockIdx.x;
    const int b = bid >> 5, j = bid & 31, h = j;      // row, slice; head = (j<8)
    int* rf = p.rflags + b * 64;

    for (int t = 0; t < LLEN; ++t) {
        for (int l = 0; l < NLAYER; ++l) {
            const int e = (t * NLAYER + l) << 2;
            if (j < 8) {
                // ======== PA ========
                rwait(rf, 32, e, tid);
                if (l == 0) {
                    if (t > 0) {
                        stage_row(rs, p.y3 + b * DD, scr, tid, 1);
                        {
                            int cl = tid & 127, kh = tid >> 7;
                            const __half2* w2 = (const __half2*)(p.clfGW16 + (size_t)cl * 512 + kh * 256);
                            const float* xh = rs + kh * 256;
                            float lg = 0.f;
                            #pragma unroll 8
                            for (int k2 = 0; k2 < 128; ++k2) {
                                float2 fw = __half22float2(w2[k2]);
                                lg += xh[2 * k2] * fw.x + xh[2 * k2 + 1] * fw.y;
                            }
                            part[tid] = lg;
                        }
                        __syncthreads();
                        if (tid < 128) {
                            float m = scr[8], ri = scr[9];
                            float lg = ri * ((part[tid] + part[128 + tid]) - m * p.clfSGW[tid]) + p.clfBW[tid];
                            if (h == 0) p.out_logits[((size_t)b * LLEN + (t - 1)) * VV + tid] = lg;
                            float bv = lg; int bi = tid;
                            for (int off = 32; off; off >>= 1) {
                                float ov = __shfl_xor(bv, off); int oi = __shfl_xor(bi, off);
                                if (ov > bv || (ov == bv && oi < bi)) { bv = ov; bi = oi; }
                            }
                            if ((tid & 63) == 0) { argv[tid >> 6] = bv; argi[tid >> 6] = bi; }
                        }
                        __syncthreads();
                        if (tid == 0) {
                            int best = (argv[1] > argv[0] || (argv[1] == argv[0] && argi[1] < argi[0]))
                                           ? argi[1] : argi[0];
                            tokS = best;
                            if (h == 0) icstore(p.tokens + b * (LLEN + 1) + t, best);
                        }
                        __syncthreads();
                    } else {
                        if (tid == 0) tokS = icload(p.tokens + b * (LLEN + 1));
                        __syncthreads();
                    }
                    const int tok = tokS;
                    {
                        const float* er = p.emb + (size_t)tok * DD;
                        const float* pr = p.peR + (size_t)t * DD;
                        rs[tid * 2]     = er[tid * 2] * EMB_SCALE + pr[tid * 2];
                        rs[tid * 2 + 1] = er[tid * 2 + 1] * EMB_SCALE + pr[tid * 2 + 1];
                    }
                    {
                        const float* eq = p.EQ + (size_t)tok * (3 * DD);
                        const float* pq = p.PEQ + (size_t)t * (3 * DD);
                        if (tid < 64) qsh[tid] = eq[h * HDIM + tid] + pq[h * HDIM + tid];
                        else if (tid < 128) {
                            int c = tid - 64;
                            kvK[t * KVP + c] = eq[DD + h * HDIM + c] + pq[DD + h * HDIM + c];
                        } else if (tid < 192) {
                            int c = tid - 128;
                            kvV[t * KVP + c] = eq[2 * DD + h * HDIM + c] + pq[2 * DD + h * HDIM + c];
                        }
                    }
                    __syncthreads();
                } else {
                    stage_row(rs, p.y3 + b * DD, scr, tid, 1);     // LN3 stats
                    const float m0 = scr[8], r0 = scr[9];
                    const int c = tid & 63, ks = tid >> 6;
                    #pragma unroll
                    for (int m = 0; m < 3; ++m) {
                        const __half2* w2 = (const __half2*)(p.qkvGW16 +
                            ((size_t)((l - 1) * 1536 + m * 512 + h * HDIM + c)) * WLD + ks * 128);
                        const float* x0 = rs + ks * 128;
                        float a = 0.f;
                        #pragma unroll 16
                        for (int i2 = 0; i2 < 64; ++i2) {
                            float2 fw = __half22float2(w2[i2]);
                            a += x0[2 * i2] * fw.x + x0[2 * i2 + 1] * fw.y;
                        }
                        part[m * 256 + ks * 64 + c] = a;
                    }
                    __syncthreads();
                    if (tid < 192) {
                        int m = tid >> 6, c2 = tid & 63;
                        float raw = part[m * 256 + c2] + part[m * 256 + 64 + c2]
                                  + part[m * 256 + 128 + c2] + part[m * 256 + 192 + c2];
                        int gc = (l - 1) * 1536 + m * 512 + h * HDIM + c2;
                        float val = r0 * (raw - m0 * p.qkvSGW[gc]) + p.qkvBW[gc];
                        if (m == 0)      qsh[c2] = val;
                        else if (m == 1) kvK[(l * LLEN + t) * KVP + c2] = val;
                        else             kvV[(l * LLEN + t) * KVP + c2] = val;
                    }
                    __syncthreads();
                }
                // self-attn over LDS KV
                if (tid <= t) {
                    const float* kr = kvK + (l * LLEN + tid) * KVP;
                    float s = 0.f;
                    #pragma unroll 16
                    for (int d = 0; d < HDIM; ++d) s += qsh[d] * kr[d];
                    part[tid] = s * 0.125f;
                }
                __syncthreads();
                if (tid < 64) {
                    float s = (tid <= t) ? part[tid] : -1e30f;
                    float mx = s;
                    for (int off = 32; off; off >>= 1) mx = fmaxf(mx, __shfl_xor(mx, off));
                    float pe = (tid <= t) ? expf(s - mx) : 0.f;
                    float sum = pe;
                    for (int off = 32; off; off >>= 1) sum += __shfl_xor(sum, off);
                    if (tid <= t) part[tid] = pe / sum;
                }
                __syncthreads();
                if (tid < 64) {
                    float o = 0.f;
                    for (int jj = 0; jj <= t; ++jj) o += part[jj] * kvV[(l * LLEN + jj) * KVP + tid];
                    part[64 + tid] = o;
                }
                __syncthreads();
                // saout-fold -> atomic y1acc
                {
                    const int c0 = tid * 2;
                    const float m0 = scr[8], r0 = scr[9];
                    const __half* w0 = p.saout16 + ((size_t)(l * 512 + c0)) * WLD + h * HDIM;
                    const __half* w1 = w0 + WLD;
                    float a0 = 0.f, a1 = 0.f;
                    #pragma unroll 16
                    for (int d = 0; d < HDIM; ++d) {
                        float pv = part[64 + d];
                        a0 += pv * __half2float(w0[d]);
                        a1 += pv * __half2float(w1[d]);
                    }
                    if (h == 0) {
                        float x0r = rs[c0], x1r = rs[c0 + 1];
                        if (l > 0) {
                            x0r = (x0r - m0) * r0 * p.ln3_g[(l - 1) * DD + c0] + p.ln3_b[(l - 1) * DD + c0];
                            x1r = (x1r - m0) * r0 * p.ln3_g[(l - 1) * DD + c0 + 1] + p.ln3_b[(l - 1) * DD + c0 + 1];
                        }
                        a0 += p.sa_out_b[l * DD + c0] + x0r;
                        a1 += p.sa_out_b[l * DD + c0 + 1] + x1r;
                    }
                    atomicAdd(p.y1acc + b * DD + c0, a0);
                    atomicAdd(p.y1acc + b * DD + c0 + 1, a1);
                }
                if (tid < 64) cstore(p.y2acc + b * DD + h * HDIM + tid, 0.f);
                rarrive(rf, j, e + 1);

                // ======== PB ========
                rwait(rf, 8, e + 1, tid);
                stage_row(rs, p.y1acc + b * DD, scr, tid, 1);      // LN1 stats
                const float m0 = scr[8], r0 = scr[9];
                {
                    const int c = tid & 63, ks = tid >> 6;
                    const __half2* w2 = (const __half2*)(p.caq16 +
                        ((size_t)(l * 512 + h * HDIM + c)) * WLD + ks * 128);
                    const float* x0 = rs + ks * 128;
                    float a = 0.f;
                    #pragma unroll 16
                    for (int i2 = 0; i2 < 64; ++i2) {
                        float2 fw = __half22float2(w2[i2]);
                        a += x0[2 * i2] * fw.x + x0[2 * i2 + 1] * fw.y;
                    }
                    part[ks * 64 + c] = a;
                }
                __syncthreads();
                if (tid < 64) {
                    float raw = part[tid] + part[64 + tid] + part[128 + tid] + part[192 + tid];
                    int gc = l * 512 + h * HDIM + tid;
                    qsh[tid] = r0 * (raw - m0 * p.caqSGW[gc]) + p.caqBW[gc];
                }
                __syncthreads();
                float* sc = part + 256;
                if (tid < 128) {
                    const float* kp = p.Kmem + (((size_t)(l * 8 + b)) * SMEMN + tid) * DD + h * HDIM;
                    float s = 0.f;
                    #pragma unroll 8
                    for (int d = 0; d < HDIM; ++d) s += qsh[d] * kp[d];
                    sc[tid] = s * 0.125f;
                }
                __syncthreads();
                if (tid < 64) {
                    float s0 = sc[tid], s1 = sc[tid + 64];
                    float mx = fmaxf(s0, s1);
                    for (int off = 32; off; off >>= 1) mx = fmaxf(mx, __shfl_xor(mx, off));
                    float e0 = expf(s0 - mx), e1 = expf(s1 - mx);
                    float sum = e0 + e1;
                    for (int off = 32; off; off >>= 1) sum += __shfl_xor(sum, off);
                    sc[tid] = e0 / sum; sc[tid + 64] = e1 / sum;
                }
                __syncthreads();
                float* po = part + 384;
                if (tid < 128) {
                    int d = tid & 63, half = tid >> 6;
                    const float* Vb = p.Vmem + (((size_t)(l * 8 + b)) * SMEMN + half * 64) * DD + h * HDIM + d;
                    float o = 0.f;
                    for (int jj = 0; jj < 64; ++jj) o += sc[half * 64 + jj] * Vb[(size_t)jj * DD];
                    po[half * 64 + d] = o;
                }
                __syncthreads();
                if (tid < 64) part[512 + tid] = po[tid] + po[64 + tid];
                __syncthreads();
                {
                    const int c0 = tid * 2;
                    const __half* w0 = p.caout16 + ((size_t)(l * 512 + c0)) * WLD + h * HDIM;
                    const __half* w1 = w0 + WLD;
                    float a0 = 0.f, a1 = 0.f;
                    #pragma unroll 16
                    for (int d = 0; d < HDIM; ++d) {
                        float cv = part[512 + d];
                        a0 += cv * __half2float(w0[d]);
                        a1 += cv * __half2float(w1[d]);
                    }
                    if (h == 0) {
                        float r0v = (rs[c0] - m0) * r0 * p.ln1_g[l * DD + c0] + p.ln1_b[l * DD + c0];
                        float r1v = (rs[c0 + 1] - m0) * r0 * p.ln1_g[l * DD + c0 + 1] + p.ln1_b[l * DD + c0 + 1];
                        a0 += p.ca_out_b[l * DD + c0] + r0v;
                        a1 += p.ca_out_b[l * DD + c0 + 1] + r1v;
                    }
                    atomicAdd(p.y2acc + b * DD + c0, a0);
                    atomicAdd(p.y2acc + b * DD + c0 + 1, a1);
                }
                rarrive(rf, j, e + 2);
            }

            // ======== PC: ffn1 64-col slice, LN2-folded + relu (all 32) ========
            rwait(rf, 8, e + 2, tid);
            stage_row(rs, p.y2acc + b * DD, scr, tid, 1);
            {
                const int c = tid >> 2, ks = tid & 3;
                const int gc = j * 64 + c;
                const __half2* w2 = (const __half2*)(p.ffn116 +
                    ((size_t)(l * 2048 + gc)) * WLD + ks * 128);
                const float* x0 = rs + ks * 128;
                float a = 0.f;
                #pragma unroll 16
                for (int i2 = 0; i2 < 64; ++i2) {
                    float2 fw = __half22float2(w2[i2]);
                    a += x0[2 * i2] * fw.x + x0[2 * i2 + 1] * fw.y;
                }
                a += __shfl_down(a, 2, 4);
                a += __shfl_down(a, 1, 4);
                if (ks == 0) {
                    float m0 = scr[8], r0 = scr[9];
                    float val = r0 * (a - m0 * p.ffn1SGW[l * DFFN + gc]) + p.ffn1BW[l * DFFN + gc];
                    cstore(p.hb + b * DFFN + gc, fmaxf(val, 0.f));
                }
            }
            if (tid < 16) cstore(p.y1acc + b * DD + j * 16 + tid, 0.f);
            rarrive(rf, j, e + 3);

            // ======== PD: ffn2 16-col slice + LN2 residual (all 32) ========
            rwait(rf, 32, e + 3, tid);
            {
                #pragma unroll
                for (int u = 0; u < 4; ++u) {
                    int k = u * 512 + tid * 2;
                    float2 v = cload2(p.hb + b * DFFN + k);
                    *(float2*)(xs + (k >> 7) * 130 + (k & 127)) = v;
                }
                __syncthreads();
                const int c = tid >> 4, ks = tid & 15;
                const int gc = j * 16 + c;
                const __half2* w2 = (const __half2*)(p.ffn216 +
                    ((size_t)(l * 512 + gc)) * WLD2 + ks * 128);
                const float* x0 = xs + ks * 130;
                float a = 0.f;
                #pragma unroll 16
                for (int i2 = 0; i2 < 64; ++i2) {
                    float2 fw = __half22float2(w2[i2]);
                    a += x0[2 * i2] * fw.x + x0[2 * i2 + 1] * fw.y;
                }
                for (int off = 8; off; off >>= 1) a += __shfl_down(a, off, 16);
                if (ks == 0) {
                    float m0 = scr[8], r0 = scr[9];
                    float val = a + p.ffn_b2[l * DD + gc]
                              + (rs[gc] - m0) * r0 * p.ln2_g[l * DD + gc] + p.ln2_b[l * DD + gc];
                    cstore(p.y3 + b * DD + gc, val);
                }
                __syncthreads();
            }
            rarrive(rf, j, e + 4);
        }
    }

    // ---- epilogue: final-step clf (block j==0 per row) ----
    if (j == 0) {
        rwait(rf, 32, (LLEN * NLAYER) << 2, tid);
        stage_row(rs, p.y3 + b * DD, scr, tid, 1);
        {
            int cl = tid & 127, kh = tid >> 7;
            const __half2* w2 = (const __half2*)(p.clfGW16 + (size_t)cl * 512 + kh * 256);
            const float* xh = rs + kh * 256;
            float lg = 0.f;
            #pragma unroll 8
            for (int k2 = 0; k2 < 128; ++k2) {
                float2 fw = __half22float2(w2[k2]);
                lg += xh[2 * k2] * fw.x + xh[2 * k2 + 1] * fw.y;
            }
            part[tid] = lg;
        }
        __syncthreads();
        if (tid < 128) {
            float m = scr[8], ri = scr[9];
            float lg = ri * ((part[tid] + part[128 + tid]) - m * p.clfSGW[tid]) + p.clfBW[tid];
            p.out_logits[((size_t)b * LLEN + (LLEN - 1)) * VV + tid] = lg;
            float bv = lg; int bi = tid;
            for (int off = 32; off; off >>= 1) {
                float ov = __shfl_xor(bv, off); int oi = __shfl_xor(bi, off);
                if (ov > bv || (ov == bv && oi < bi)) { bv = ov; bi = oi; }
            }
            if ((tid & 63) == 0) { argv[tid >> 6] = bv; argi[tid >> 6] = bi; }
        }
        __syncthreads();
        if (tid == 0) {
            int best = (argv[1] > argv[0] || (argv[1] == argv[0] && argi[1] < argi[0]))
                           ? argi[1] : argi[0];
            icstore(p.tokens + b * (LLEN + 1) + LLEN, best);
        }
        asm volatile("s_waitcnt vmcnt(0)" ::: "memory");
        __syncthreads();
        if (tid == 0) icstore(p.clfflag + b * 16, 1);
    }

    // ---- finalize sampled (block 0) ----
    if (bid == 0) {
        if (tid < 8) {
            int spins = 0;
            while (icload(p.clfflag + tid * 16) < 1) {
                __builtin_amdgcn_s_sleep(2);
                if (++spins > (1 << 17)) break;
            }
        }
        __syncthreads();
        if (tid < BB) {
            int bb = tid;
            int toks[LLEN + 1];
            for (int jj = 0; jj <= LLEN; jj++) toks[jj] = icload(p.tokens + bb * (LLEN + 1) + jj);
            int eos = 0;
            for (int jj = 1; jj <= LLEN; jj++)
                if (toks[jj] == EOS_T) { eos = jj; break; }
            for (int jj = 0; jj <= LLEN; jj++) {
                int v = toks[jj];
                if (eos != 0 && jj > eos + 1) v = PAD_T;
                p.out_sampled[bb * (LLEN + 1) + jj] = (float)v;
            }
        }
    }
}

// --------------------------------------------------------------------- host
extern "C" void kernel_launch(void* const* d_in, const int* in_sizes, int n_in,
                              void* d_out, int out_size, void* d_ws, size_t ws_size,
                              hipStream_t stream) {
    const float* memory   = (const float*)d_in[0];
    const float* emb      = (const float*)d_in[1];
    const float* sa_qkv_w = (const float*)d_in[2];
    const float* sa_qkv_b = (const float*)d_in[3];
    const float* sa_out_w = (const float*)d_in[4];
    const float* sa_out_b = (const float*)d_in[5];
    const float* ca_q_w   = (const float*)d_in[6];
    const float* ca_q_b   = (const float*)d_in[7];
    const float* ca_kv_w  = (const float*)d_in[8];
    const float* ca_kv_b  = (const float*)d_in[9];
    const float* ca_out_w = (const float*)d_in[10];
    const float* ca_out_b = (const float*)d_in[11];
    const float* ln1_g    = (const float*)d_in[12];
    const float* ln1_b    = (const float*)d_in[13];
    const float* ln2_g    = (const float*)d_in[14];
    const float* ln2_b    = (const float*)d_in[15];
    const float* ln3_g    = (const float*)d_in[16];
    const float* ln3_b    = (const float*)d_in[17];
    const float* ffn_w1   = (const float*)d_in[18];
    const float* ffn_b1   = (const float*)d_in[19];
    const float* ffn_w2   = (const float*)d_in[20];
    const float* ffn_b2   = (const float*)d_in[21];
    const float* clf_w    = (const float*)d_in[22];
    const float* clf_b    = (const float*)d_in[23];

    float* f   = (float*)d_ws;
    int*   wsI = (int*)d_ws;
    int* rflags  = wsI;            // 8 x 64 ints
    int* clfflag = wsI + 512;      // 128 ints
    int* tokens  = wsI + 640;      // 264 ints
    float* y1acc = f + 1024;       // 4096
    float* y2acc = f + 5120;       // 4096
    float* peR   = f + 9216;       // 16384
    float* Kmem  = peR + (size_t)LLEN * DD;
    float* Vmem  = Kmem + (size_t)NLAYER * BB * SMEMN * DD;
    float* hb    = Vmem + (size_t)NLAYER * BB * SMEMN * DD;
    float* y3    = hb + BB * DFFN;
    float* EQ    = y3 + BB * DD;
    float* PEQ   = EQ + (size_t)VV * 3 * DD;
    float* qkvSGW = PEQ + (size_t)LLEN * 3 * DD;
    float* qkvBW  = qkvSGW + 2 * 1536;
    float* caqSGW = qkvBW + 2 * 1536;
    float* caqBW  = caqSGW + 3 * 512;
    float* ffn1SGW = caqBW + 3 * 512;
    float* ffn1BW  = ffn1SGW + 3 * 2048;
    float* clfSGW  = ffn1BW + 3 * 2048;
    float* clfBW   = clfSGW + 128;
    __half* qkvGW16 = (__half*)(clfBW + 128);
    __half* saout16 = qkvGW16 + (size_t)2 * 1536 * WLD;
    __half* caq16   = saout16 + (size_t)3 * 512 * WLD;
    __half* caout16 = caq16   + (size_t)3 * 512 * WLD;
    __half* ffn116  = caout16 + (size_t)3 * 512 * WLD;
    __half* ffn216  = ffn116  + (size_t)3 * 2048 * WLD;
    __half* clfGW16 = ffn216  + (size_t)3 * 512 * WLD2;

    float* out_logits  = (float*)d_out;
    float* out_sampled = out_logits + (size_t)BB * LLEN * VV;

    hipMemsetAsync(d_ws, 0, 40960, stream);

    ProParams q;
    q.memory = memory; q.emb = emb;
    q.sa_qkv_w = sa_qkv_w; q.sa_qkv_b = sa_qkv_b; q.sa_out_w = sa_out_w;
    q.ca_q_w = ca_q_w; q.ca_q_b = ca_q_b; q.ca_kv_w = ca_kv_w; q.ca_kv_b = ca_kv_b;
    q.ca_out_w = ca_out_w;
    q.ln1_g = ln1_g; q.ln1_b = ln1_b; q.ln2_g = ln2_g; q.ln2_b = ln2_b;
    q.ln3_g = ln3_g; q.ln3_b = ln3_b;
    q.ffn_w1 = ffn_w1; q.ffn_b1 = ffn_b1; q.ffn_w2 = ffn_w2;
    q.clf_w = clf_w; q.clf_b = clf_b;
    q.tokens = tokens; q.peR = peR; q.Kmem = Kmem; q.Vmem = Vmem;
    q.EQ = EQ; q.PEQ = PEQ;
    q.qkvSGW = qkvSGW; q.qkvBW = qkvBW; q.caqSGW = caqSGW; q.caqBW = caqBW;
    q.ffn1SGW = ffn1SGW; q.ffn1BW = ffn1BW; q.clfSGW = clfSGW; q.clfBW = clfBW;
    q.qkvGW16 = qkvGW16; q.saout16 = saout16; q.caq16 = caq16; q.caout16 = caout16;
    q.ffn116 = ffn116; q.ffn216 = ffn216; q.clfGW16 = clfGW16;
    k_prologue<<<11020, 256, 0, stream>>>(q);

    MegaParams p;
    p.emb = emb;
    p.sa_out_b = sa_out_b; p.ca_out_b = ca_out_b; p.ffn_b2 = ffn_b2;
    p.ln1_g = ln1_g; p.ln1_b = ln1_b;
    p.ln2_g = ln2_g; p.ln2_b = ln2_b;
    p.ln3_g = ln3_g; p.ln3_b = ln3_b;
    p.qkvGW16 = qkvGW16; p.saout16 = saout16; p.caq16 = caq16; p.caout16 = caout16;
    p.ffn116 = ffn116; p.ffn216 = ffn216; p.clfGW16 = clfGW16;
    p.qkvSGW = qkvSGW; p.qkvBW = qkvBW; p.caqSGW = caqSGW; p.caqBW = caqBW;
    p.ffn1SGW = ffn1SGW; p.ffn1BW = ffn1BW; p.clfSGW = clfSGW; p.clfBW = clfBW;
    p.EQ = EQ; p.PEQ = PEQ; p.peR = peR;
    p.tokens = tokens; p.rflags = rflags; p.clfflag = clfflag;
    p.Kmem = Kmem; p.Vmem = Vmem;
    p.y1acc = y1acc; p.y2acc = y2acc; p.hb = hb; p.y3 = y3;
    p.out_logits = out_logits; p.out_sampled = out_sampled;

    mega_kernel<<<NB, 256, 0, stream>>>(p);
}